// Round 22
// baseline (814.051 us; speedup 1.0000x reference)
//
#include <hip/hip_runtime.h>
#include <hip/hip_bf16.h>

#define TPB 256

struct ParCfg { int zoff[9]; int kper[8]; };

// ================= masks =================
__global__ __launch_bounds__(TPB) void k_mask0(const float* __restrict__ mask,
                                               float* __restrict__ m0, int n) {
  int i = blockIdx.x * TPB + threadIdx.x;
  if (i < n) m0[i] = (mask[i] < 0.1f) ? 1.0f : 0.0f;
}

__global__ __launch_bounds__(TPB) void k_downmask(const float* __restrict__ mi,
                                                  float* __restrict__ mo, int Dout) {
  int n = Dout * Dout * Dout;
  int idx = blockIdx.x * TPB + threadIdx.x;
  if (idx >= n) return;
  int Din = Dout * 2;
  int ox = idx % Dout, oy = (idx / Dout) % Dout, oz = idx / (Dout * Dout);
  float v = 0.f;
  for (int kz = 0; kz < 3; kz++) {
    int iz = 2 * oz + kz - 1; if ((unsigned)iz >= (unsigned)Din) continue;
    for (int ky = 0; ky < 3; ky++) {
      int iy = 2 * oy + ky - 1; if ((unsigned)iy >= (unsigned)Din) continue;
      for (int kx = 0; kx < 3; kx++) {
        int ix = 2 * ox + kx - 1; if ((unsigned)ix >= (unsigned)Din) continue;
        v = fmaxf(v, mi[(iz * Din + iy) * Din + ix]);
      }
    }
  }
  mo[idx] = v;
}

__global__ __launch_bounds__(TPB) void k_maskx(const float* __restrict__ x,
                                               const float* __restrict__ m,
                                               float* __restrict__ o,
                                               long total, int vox) {
  long i = blockIdx.x * (long)TPB + threadIdx.x;
  if (i < total) o[i] = x[i] * m[i % vox];
}

__global__ __launch_bounds__(TPB) void k_sumparts(const float* __restrict__ parts,
                                                  float* __restrict__ out,
                                                  long n, int s) {
  long i = blockIdx.x * (long)TPB + threadIdx.x;
  if (i >= n) return;
  float a = 0.f;
  for (int j = 0; j < s; j++) a += parts[(long)j * n + i];
  out[i] = a;
}

// all-classes sum+scatter for the merged convT kernel
__global__ __launch_bounds__(TPB) void k_sumscatA(const float* __restrict__ parts,
                                                  float* __restrict__ out,
                                                  int lgNp, int lgMN, int Dh,
                                                  int lgDh, ParCfg pc) {
  long idx = blockIdx.x * (long)TPB + threadIdx.x;
  if (idx >= (8L << lgMN)) return;
  int cls = (int)(idx >> lgMN);
  int r = (int)(idx & ((1L << lgMN) - 1));
  int co = r >> lgNp;
  int pp = r & ((1 << lgNp) - 1);
  float s = 0.f;
  for (int z = pc.zoff[cls]; z < pc.zoff[cls + 1]; z++)
    s += parts[((long)z << lgMN) + r];
  int px = cls & 1, py = (cls >> 1) & 1, pz = (cls >> 2) & 1;
  int ox = pp & (Dh - 1), oy = (pp >> lgDh) & (Dh - 1), oz = pp >> (2 * lgDh);
  int DF = Dh * 2;
  long fc = ((long)(2 * oz + pz) * DF + (2 * oy + py)) * DF + (2 * ox + px);
  out[(long)co * ((long)DF * DF * DF) + fc] = s;
}

// ================= N=8 weight-streaming path (btd, btc) =================
__global__ __launch_bounds__(TPB) void k_bcol8(const float* __restrict__ in,
                                               float* __restrict__ Bcol,
                                               int K, int Din, int mode) {
  long idx = blockIdx.x * (long)TPB + threadIdx.x;
  if (idx >= (long)K * 8) return;
  int kg = (int)(idx >> 3), pp = (int)(idx & 7);
  int ci = kg / 27, tap = kg - ci * 27;
  int kz = tap / 9, r9 = tap - kz * 9;
  int ky = r9 / 3, kx = r9 - ky * 3;
  int oz = pp >> 2, oy = (pp >> 1) & 1, ox = pp & 1;
  int iz, iy, ix;
  if (mode == 0) { iz = 2 * oz + kz - 1; iy = 2 * oy + ky - 1; ix = 2 * ox + kx - 1; }
  else           { iz = oz + kz - 1;     iy = oy + ky - 1;     ix = ox + kx - 1; }
  float v = 0.f;
  if ((unsigned)iz < (unsigned)Din && (unsigned)iy < (unsigned)Din &&
      (unsigned)ix < (unsigned)Din)
    v = in[(long)ci * Din * Din * Din + ((long)iz * Din + iy) * Din + ix];
  Bcol[idx] = v;
}

// 4 rows per block: every Bcol load amortized over 4 weight rows.
__global__ __launch_bounds__(TPB) void k_gemv8d(const float* __restrict__ W,
                                                const float* __restrict__ Bcol,
                                                float* __restrict__ part,
                                                int M, int K, int kqPer) {
  const int t = threadIdx.x;
  const int co0 = blockIdx.x * 4;
  const int kq = K >> 2;
  int q0 = blockIdx.y * kqPer;
  int q1 = q0 + kqPer; if (q1 > kq) q1 = kq;
  float acc[4][8];
#pragma unroll
  for (int r = 0; r < 4; r++)
#pragma unroll
    for (int p = 0; p < 8; p++) acc[r][p] = 0.f;
  const float4* W4 = (const float4*)W;
  for (int i = q0 + t; i < q1; i += TPB) {
    float4 w4[4];
#pragma unroll
    for (int r = 0; r < 4; r++) w4[r] = W4[(long)(co0 + r) * kq + i];
    const float* bp = &Bcol[(long)i * 32];
#pragma unroll
    for (int j = 0; j < 4; j++) {
      const float4 b0 = *(const float4*)&bp[j * 8];
      const float4 b1 = *(const float4*)&bp[j * 8 + 4];
#pragma unroll
      for (int r = 0; r < 4; r++) {
        const float w = (j == 0) ? w4[r].x : (j == 1) ? w4[r].y
                        : (j == 2) ? w4[r].z : w4[r].w;
        acc[r][0] += w * b0.x; acc[r][1] += w * b0.y;
        acc[r][2] += w * b0.z; acc[r][3] += w * b0.w;
        acc[r][4] += w * b1.x; acc[r][5] += w * b1.y;
        acc[r][6] += w * b1.z; acc[r][7] += w * b1.w;
      }
    }
  }
#pragma unroll
  for (int off = 32; off > 0; off >>= 1)
#pragma unroll
    for (int r = 0; r < 4; r++)
#pragma unroll
      for (int p = 0; p < 8; p++) acc[r][p] += __shfl_down(acc[r][p], off);
  __shared__ float Rs[4][4][8];
  if ((t & 63) == 0) {
#pragma unroll
    for (int r = 0; r < 4; r++)
#pragma unroll
      for (int p = 0; p < 8; p++) Rs[t >> 6][r][p] = acc[r][p];
  }
  __syncthreads();
  if (t < 32) {
    int r = t >> 3, p = t & 7;
    part[((long)blockIdx.y * M + co0 + r) * 8 + p] =
        Rs[0][r][p] + Rs[1][r][p] + Rs[2][r][p] + Rs[3][r][p];
  }
}

// ============ up0 path: compact parity im2colT (Din=2 -> Dout=4) ============
__global__ __launch_bounds__(TPB) void k_bcolT(const float* __restrict__ in,
                                               float* __restrict__ Bcol, int K) {
  long idx = blockIdx.x * (long)TPB + threadIdx.x;
  if (idx >= (long)K * 8) return;
  int kg = (int)(idx >> 3), pp = (int)(idx & 7);
  int ci = kg / 27, tap = kg - ci * 27;
  int kz = tap / 9, r9 = tap - kz * 9;
  int ky = r9 / 3, kx = r9 - ky * 3;
  int oxh = pp & 1, oyh = (pp >> 1) & 1, ozh = pp >> 2;
  int cx = (kx + (kx & 1)) >> 1;
  int cy = (ky + (ky & 1)) >> 1;
  int cz = (kz + (kz & 1)) >> 1;
  int ix = oxh + cx - 1, iy = oyh + cy - 1, iz = ozh + cz - 1;
  float v = 0.f;
  if ((unsigned)ix < 2u && (unsigned)iy < 2u && (unsigned)iz < 2u)
    v = in[(long)ci * 8 + (iz * 2 + iy) * 2 + ix];
  Bcol[idx] = v;
}

__global__ __launch_bounds__(TPB) void k_gemvT64(const float* __restrict__ W,
                                                 const float* __restrict__ Bcol,
                                                 float* __restrict__ part,
                                                 int M, int Cin, int ciPer) {
  __shared__ float Ws[256 * 27];
  const int t = threadIdx.x;
  const int row = blockIdx.x;
  int ci0 = blockIdx.y * ciPer;
  int ci1 = ci0 + ciPer; if (ci1 > Cin) ci1 = Cin;

  float acc[8][8];
#pragma unroll
  for (int c = 0; c < 8; c++)
#pragma unroll
    for (int p = 0; p < 8; p++) acc[c][p] = 0.f;

  for (int cb = ci0; cb < ci1; cb += 256) {
    int nci = ci1 - cb; if (nci > 256) nci = 256;
    int nf = nci * 27;
    for (int i = t; i < nf; i += TPB)
      Ws[i] = W[(long)row * Cin * 27 + (long)cb * 27 + i];
    __syncthreads();
    if (t < nci) {
      const float* bp = &Bcol[((long)(cb + t) * 27) * 8];
      const float* wp = &Ws[t * 27];
#pragma unroll
      for (int tap = 0; tap < 27; tap++) {
        const int kz = tap / 9, r9 = tap - kz * 9;
        const int ky = r9 / 3, kx = r9 - ky * 3;
        const int cls = ((kz & 1) << 2) | ((ky & 1) << 1) | (kx & 1);
        const float w = wp[tap];
        const float4 b0 = *(const float4*)&bp[tap * 8];
        const float4 b1 = *(const float4*)&bp[tap * 8 + 4];
        acc[cls][0] += w * b0.x; acc[cls][1] += w * b0.y;
        acc[cls][2] += w * b0.z; acc[cls][3] += w * b0.w;
        acc[cls][4] += w * b1.x; acc[cls][5] += w * b1.y;
        acc[cls][6] += w * b1.z; acc[cls][7] += w * b1.w;
      }
    }
    __syncthreads();
  }

#pragma unroll
  for (int off = 32; off > 0; off >>= 1)
#pragma unroll
    for (int c = 0; c < 8; c++)
#pragma unroll
      for (int p = 0; p < 8; p++) acc[c][p] += __shfl_down(acc[c][p], off);
  __shared__ float Rs[4][64];
  if ((t & 63) == 0) {
#pragma unroll
    for (int c = 0; c < 8; c++)
#pragma unroll
      for (int p = 0; p < 8; p++) Rs[t >> 6][c * 8 + p] = acc[c][p];
  }
  __syncthreads();
  if (t < 64)
    part[((long)blockIdx.y * M + row) * 64 + t] =
        Rs[0][t] + Rs[1][t] + Rs[2][t] + Rs[3][t];
}

__global__ __launch_bounds__(TPB) void k_sumscatT(const float* __restrict__ parts,
                                                  float* __restrict__ out,
                                                  int M, int Z) {
  long idx = blockIdx.x * (long)TPB + threadIdx.x;
  if (idx >= (long)M * 64) return;
  int row = (int)(idx >> 6), q = (int)(idx & 63);
  float s = 0.f;
  for (int z = 0; z < Z; z++) s += parts[((long)z * M + row) * 64 + q];
  int cls = q >> 3, p = q & 7;
  int px = cls & 1, py = (cls >> 1) & 1, pz = (cls >> 2) & 1;
  int oxh = p & 1, oyh = (p >> 1) & 1, ozh = p >> 2;
  int fc = (2 * ozh + pz) * 16 + (2 * oyh + py) * 4 + (2 * oxh + px);
  out[(long)row * 64 + fc] = s;
}

// ================= tiled implicit-GEMM, split-K, reg-prefetch =================
// MODE 0: conv k3 s2 p1   MODE 2: 1x1 concat-fuse   MODE 3: conv k3 s1 p1
template<int MT, int MODE>
__global__ __launch_bounds__(TPB) void k_gemm(const float* __restrict__ A,
                                              const float* __restrict__ B1,
                                              const float* __restrict__ B2,
                                              float* __restrict__ C,
                                              int M, int N, int K,
                                              int Din, int Dout, int C1,
                                              int kcPer) {
  constexpr int MR = MT / 16;
  constexpr int AEL = (MT == 64) ? 8 : 2;
  __shared__ __align__(16) float At[32][MT];
  __shared__ __align__(16) float Bt[32][64];

  const int t = threadIdx.x;
  const int n0 = blockIdx.x * 64;
  const int m0 = blockIdx.y * MT;

  const int p0 = (t & 15) * 4;
  const int co0 = (t >> 4) * MR;

  const int pb = t & 63;
  const int kb0 = (t >> 6) * 8;
  const int pp = n0 + pb;
  const int oxb = pp & (Dout - 1);
  const int oyb = (pp / Dout) & (Dout - 1);
  const int ozb = pp / (Dout * Dout);

  const int nch = (K + 31) >> 5;
  const int c0 = blockIdx.z * kcPer;
  int c1 = c0 + kcPer; if (c1 > nch) c1 = nch;

  float acc[MR][4];
#pragma unroll
  for (int a = 0; a < MR; a++)
#pragma unroll
    for (int b = 0; b < 4; b++) acc[a][b] = 0.f;

  float raf[AEL];
  float rb[8];
  const int co_a = (MT == 64) ? (t >> 2) : (t & 15);
  const int ka   = (MT == 64) ? ((t & 3) * 8) : ((t >> 4) * 2);
  const long arow = (long)(m0 + co_a) * K;

  auto loadA = [&](int c) {
    const int k0 = c << 5;
    if (MT == 64) {
#pragma unroll
      for (int j = 0; j < 2; j++) {
        const int kg = k0 + ka + j * 4;
        float4 v = (kg < K) ? *(const float4*)&A[arow + kg]
                            : make_float4(0.f, 0.f, 0.f, 0.f);
        raf[j * 4 + 0] = v.x; raf[j * 4 + 1] = v.y;
        raf[j * 4 + 2] = v.z; raf[j * 4 + 3] = v.w;
      }
    } else {
      const int kg = k0 + ka;
      raf[0] = (kg < K) ? A[arow + kg] : 0.f;
      raf[1] = (kg + 1 < K) ? A[arow + kg + 1] : 0.f;
    }
  };

  auto loadB = [&](int c) {
    const int k0 = c << 5;
#pragma unroll
    for (int j = 0; j < 8; j++) {
      const int kg = k0 + kb0 + j;
      float v = 0.f;
      if (kg < K && pp < N) {
        if (MODE == 2) {
          v = (kg < C1) ? B1[(long)kg * N + pp] : B2[(long)(kg - C1) * N + pp];
        } else {
          const int ci = kg / 27;
          const int tap = kg - ci * 27;
          const int kz = tap / 9;
          const int r9 = tap - kz * 9;
          const int ky = r9 / 3;
          const int kx = r9 - ky * 3;
          int iz, iy, ix;
          bool ok;
          if (MODE == 0) {
            iz = 2 * ozb + kz - 1; iy = 2 * oyb + ky - 1; ix = 2 * oxb + kx - 1;
            ok = (unsigned)iz < (unsigned)Din && (unsigned)iy < (unsigned)Din &&
                 (unsigned)ix < (unsigned)Din;
          } else { // MODE 3
            iz = ozb + kz - 1; iy = oyb + ky - 1; ix = oxb + kx - 1;
            ok = (unsigned)iz < (unsigned)Din && (unsigned)iy < (unsigned)Din &&
                 (unsigned)ix < (unsigned)Din;
          }
          if (ok)
            v = B1[(long)ci * Din * Din * Din + ((long)iz * Din + iy) * Din + ix];
        }
      }
      rb[j] = v;
    }
  };

  if (c0 < c1) { loadA(c0); loadB(c0); }

  for (int c = c0; c < c1; ++c) {
    __syncthreads();
#pragma unroll
    for (int j = 0; j < AEL; j++) At[ka + j][co_a] = raf[j];
#pragma unroll
    for (int j = 0; j < 8; j++) Bt[kb0 + j][pb] = rb[j];
    if (c + 1 < c1) { loadA(c + 1); loadB(c + 1); }
    __syncthreads();
#pragma unroll
    for (int kk = 0; kk < 32; ++kk) {
      const float4 b4 = *(const float4*)&Bt[kk][p0];
      if (MR == 4) {
        const float4 a4 = *(const float4*)&At[kk][co0];
        acc[0][0] += a4.x * b4.x; acc[0][1] += a4.x * b4.y;
        acc[0][2] += a4.x * b4.z; acc[0][3] += a4.x * b4.w;
        acc[1][0] += a4.y * b4.x; acc[1][1] += a4.y * b4.y;
        acc[1][2] += a4.y * b4.z; acc[1][3] += a4.y * b4.w;
        acc[2][0] += a4.z * b4.x; acc[2][1] += a4.z * b4.y;
        acc[2][2] += a4.z * b4.z; acc[2][3] += a4.z * b4.w;
        acc[3][0] += a4.w * b4.x; acc[3][1] += a4.w * b4.y;
        acc[3][2] += a4.w * b4.z; acc[3][3] += a4.w * b4.w;
      } else {
        const float a = At[kk][co0];
        acc[0][0] += a * b4.x; acc[0][1] += a * b4.y;
        acc[0][2] += a * b4.z; acc[0][3] += a * b4.w;
      }
    }
  }

  float* Cz = C + (long)blockIdx.z * ((long)M * N);
#pragma unroll
  for (int mr = 0; mr < MR; mr++) {
    if (n0 + p0 < N) {
      float4 v = make_float4(acc[mr][0], acc[mr][1], acc[mr][2], acc[mr][3]);
      *(float4*)&Cz[(long)(m0 + co0 + mr) * N + n0 + p0] = v;
    }
  }
}

// ================= merged convT-parity GEMM (up1..up3) =================
// 1D grid with bijective XCD-aware remap (guide T1/m204): consecutive LOGICAL
// blocks (x fastest == A-sharing n-tiles) land on the SAME XCD, cutting
// cross-XCD A-panel re-fetch. Pure index bijection: results bit-identical.
__global__ __launch_bounds__(TPB) void k_gemmTm(const float* __restrict__ A,
                                                const float* __restrict__ B1,
                                                float* __restrict__ C,
                                                int M, int N, int Cin, int Din,
                                                ParCfg pc, int ntx, int my) {
  __shared__ __align__(16) float At[32][64];
  __shared__ __align__(16) float Bt[32][64];

  const int t = threadIdx.x;
  // XCD-aware bijective remap
  const int nwg = gridDim.x;
  const int orig = blockIdx.x;
  const int qq = nwg >> 3, rr = nwg & 7, xcd = orig & 7;
  const int l = (xcd < rr ? xcd * (qq + 1) : rr * (qq + 1) + (xcd - rr) * qq) +
                (orig >> 3);
  const int bx = l % ntx;
  const int rem = l / ntx;
  const int by = rem % my;
  const int z = rem / my;

  const int n0 = bx * 64;
  const int m0 = by * 64;

  int cls = 0;
#pragma unroll
  for (int c = 1; c < 8; c++) if (z >= pc.zoff[c]) cls = c;
  const int zi = z - pc.zoff[cls];
  const int kperc = pc.kper[cls];

  const int px = cls & 1, py = (cls >> 1) & 1, pz = (cls >> 2) & 1;
  const int lgnx = 1 - px, lgny = 1 - py;
  const int lgT = lgnx + lgny + (1 - pz);
  const int T = 1 << lgT;
  const int K = Cin << lgT;
  const int nch = K >> 5;

  const int p0 = (t & 15) * 4;
  const int co0 = (t >> 4) * 4;
  const int pb = t & 63;
  const int kb0 = (t >> 6) * 8;
  const int pp = n0 + pb;
  const int oxb = pp & (Din - 1);
  const int oyb = (pp / Din) & (Din - 1);
  const int ozb = pp / (Din * Din);
  const long vin = (long)Din * Din * Din;

  const int bz = ozb - 1 + pz, by2 = oyb - 1 + py, bx2 = oxb - 1 + px;
  const long laneOff = (long)bz * Din * Din + (long)by2 * Din + bx2;
  unsigned vmask = 0;
  if (pp < N) {
    int nz_ = pz ? 1 : 2, ny_ = py ? 1 : 2, nx_ = px ? 1 : 2;
    for (int tz = 0; tz < nz_; tz++)
      for (int ty = 0; ty < ny_; ty++)
        for (int tx = 0; tx < nx_; tx++) {
          bool ok = (unsigned)(bz + tz) < (unsigned)Din &&
                    (unsigned)(by2 + ty) < (unsigned)Din &&
                    (unsigned)(bx2 + tx) < (unsigned)Din;
          if (ok) vmask |= 1u << ((tz << (lgny + lgnx)) | (ty << lgnx) | tx);
        }
  }

  const int c0 = zi * kperc;
  int c1 = c0 + kperc; if (c1 > nch) c1 = nch;

  float acc[4][4];
#pragma unroll
  for (int a = 0; a < 4; a++)
#pragma unroll
    for (int b = 0; b < 4; b++) acc[a][b] = 0.f;

  float raf[8];
  float rb[8];
  const int co_a = t & 63;
  const int ka   = (t >> 6) * 8;
  const long abase = (long)(m0 + co_a) * Cin * 27;

  auto loadA = [&](int c) {
    const int k0 = c << 5;
#pragma unroll
    for (int j = 0; j < 8; j++) {
      const int kg = k0 + ka + j;
      float v = 0.f;
      if (kg < K) {
        int ci = kg >> lgT;
        int tt = kg & (T - 1);
        int tx = tt & ((1 << lgnx) - 1);
        int r = tt >> lgnx;
        int ty = r & ((1 << lgny) - 1);
        int tz = r >> lgny;
        int kx = px ? 1 : (tx << 1);
        int ky = py ? 1 : (ty << 1);
        int kz = pz ? 1 : (tz << 1);
        v = A[abase + ci * 27 + (kz * 3 + ky) * 3 + kx];
      }
      raf[j] = v;
    }
  };

  auto loadB = [&](int c) {
    const int k0 = c << 5;
#pragma unroll
    for (int j = 0; j < 8; j++) {
      const int kg = k0 + kb0 + j;
      float v = 0.f;
      if (kg < K) {
        int ci = kg >> lgT;
        int tt = kg & (T - 1);
        int tx = tt & ((1 << lgnx) - 1);
        int r = tt >> lgnx;
        int ty = r & ((1 << lgny) - 1);
        int tz = r >> lgny;
        long base = (long)ci * vin + (long)tz * Din * Din + ty * Din + tx;
        if ((vmask >> tt) & 1) v = B1[base + laneOff];
      }
      rb[j] = v;
    }
  };

  if (c0 < c1) { loadA(c0); loadB(c0); }

  for (int c = c0; c < c1; ++c) {
    __syncthreads();
#pragma unroll
    for (int j = 0; j < 8; j++) At[ka + j][co_a] = raf[j];
#pragma unroll
    for (int j = 0; j < 8; j++) Bt[kb0 + j][pb] = rb[j];
    if (c + 1 < c1) { loadA(c + 1); loadB(c + 1); }
    __syncthreads();
#pragma unroll
    for (int kk = 0; kk < 32; ++kk) {
      const float4 b4 = *(const float4*)&Bt[kk][p0];
      const float4 a4 = *(const float4*)&At[kk][co0];
      acc[0][0] += a4.x * b4.x; acc[0][1] += a4.x * b4.y;
      acc[0][2] += a4.x * b4.z; acc[0][3] += a4.x * b4.w;
      acc[1][0] += a4.y * b4.x; acc[1][1] += a4.y * b4.y;
      acc[1][2] += a4.y * b4.z; acc[1][3] += a4.y * b4.w;
      acc[2][0] += a4.z * b4.x; acc[2][1] += a4.z * b4.y;
      acc[2][2] += a4.z * b4.z; acc[2][3] += a4.z * b4.w;
      acc[3][0] += a4.w * b4.x; acc[3][1] += a4.w * b4.y;
      acc[3][2] += a4.w * b4.z; acc[3][3] += a4.w * b4.w;
    }
  }

  float* Cz = C + (long)z * ((long)M * N);
#pragma unroll
  for (int mr = 0; mr < 4; mr++) {
    if (n0 + p0 < N) {
      float4 v = make_float4(acc[mr][0], acc[mr][1], acc[mr][2], acc[mr][3]);
      *(float4*)&Cz[(long)(m0 + co0 + mr) * N + n0 + p0] = v;
    }
  }
}

// ================= final-up: M=16, per-column kernel, reg-prefetch ==========
__global__ __launch_bounds__(TPB) void k_finup(const float* __restrict__ A,
                                               const float* __restrict__ B1,
                                               float* __restrict__ C) {
  __shared__ __align__(16) float Ws[8192];
  const int cls = blockIdx.z;
  const int px = cls & 1, py = (cls >> 1) & 1, pz = (cls >> 2) & 1;
  const int lgnx = 1 - px, lgny = 1 - py;
  const int lgT = lgnx + lgny + (1 - pz);
  const int T = 1 << lgT;
  const int K = 64 << lgT;

  for (int idx = threadIdx.x; idx < K * 16; idx += TPB) {
    int k = idx >> 4, co = idx & 15;
    int ci = k >> lgT;
    int tt = k & (T - 1);
    int tx = tt & ((1 << lgnx) - 1);
    int r = tt >> lgnx;
    int ty = r & ((1 << lgny) - 1);
    int tz = r >> lgny;
    int kx = px ? 1 : (tx << 1);
    int ky = py ? 1 : (ty << 1);
    int kz = pz ? 1 : (tz << 1);
    Ws[idx] = A[((long)co * 64 + ci) * 27 + (kz * 3 + ky) * 3 + kx];
  }

  const int pp = blockIdx.x * TPB + threadIdx.x;
  const int oxb = pp & 31, oyb = (pp >> 5) & 31, ozb = pp >> 10;
  const int bz = ozb - 1 + pz, by = oyb - 1 + py, bx = oxb - 1 + px;
  const long laneOff = (long)bz * 1024 + by * 32 + bx;
  unsigned vmask = 0;
  {
    int nz_ = pz ? 1 : 2, ny_ = py ? 1 : 2, nx_ = px ? 1 : 2;
    for (int tz = 0; tz < nz_; tz++)
      for (int ty = 0; ty < ny_; ty++)
        for (int tx = 0; tx < nx_; tx++) {
          bool ok = (unsigned)(bz + tz) < 32u && (unsigned)(by + ty) < 32u &&
                    (unsigned)(bx + tx) < 32u;
          if (ok) vmask |= 1u << ((tz << (lgny + lgnx)) | (ty << lgnx) | tx);
        }
  }

  int toff[8];
#pragma unroll
  for (int tt = 0; tt < 8; tt++) {
    int tx = tt & ((1 << lgnx) - 1);
    int r = tt >> lgnx;
    int ty = r & ((1 << lgny) - 1);
    int tz = r >> lgny;
    toff[tt] = tz * 1024 + ty * 32 + tx;
  }
  __syncthreads();

  float acc[16];
#pragma unroll
  for (int co = 0; co < 16; co++) acc[co] = 0.f;

  float bcur[8], bnxt[8];
  auto loadG = [&](int ci, float (&bv)[8]) {
#pragma unroll
    for (int tt = 0; tt < 8; tt++) {
      if (tt < T)
        bv[tt] = ((vmask >> tt) & 1)
                     ? B1[(long)ci * 32768 + toff[tt] + laneOff] : 0.f;
      else
        bv[tt] = 0.f;
    }
  };

  loadG(0, bcur);
  for (int ci = 0; ci < 64; ci++) {
    if (ci + 1 < 64) loadG(ci + 1, bnxt);
#pragma unroll
    for (int tt = 0; tt < 8; tt++) {
      if (tt < T) {
        const float b = bcur[tt];
        const float4* wp = (const float4*)&Ws[((ci << lgT) + tt) * 16];
#pragma unroll
        for (int q = 0; q < 4; q++) {
          float4 w = wp[q];
          acc[q * 4 + 0] += w.x * b;
          acc[q * 4 + 1] += w.y * b;
          acc[q * 4 + 2] += w.z * b;
          acc[q * 4 + 3] += w.w * b;
        }
      }
    }
#pragma unroll
    for (int tt = 0; tt < 8; tt++) bcur[tt] = bnxt[tt];
  }

  const long fc = ((long)(2 * ozb + pz) * 64 + (2 * oyb + py)) * 64 +
                  (2 * oxb + px);
#pragma unroll
  for (int co = 0; co < 16; co++) C[(long)co * 262144 + fc] = acc[co];
}

// ================= hierarchical masked BN stats =================
__global__ __launch_bounds__(TPB) void k_stats1(const float* __restrict__ a,
                                                const float* __restrict__ m,
                                                float* __restrict__ part,
                                                float* __restrict__ partM,
                                                int vox, int chunk) {
  const int s = blockIdx.x, c = blockIdx.y;
  const float* ap = a + (long)c * vox + (long)s * chunk;
  const float* mp = m + (long)s * chunk;
  float s0 = 0.f, s1 = 0.f, sm = 0.f;
  for (int i = threadIdx.x; i < chunk; i += TPB) {
    float mv = mp[i];
    float v = ap[i] * mv;
    s0 += v; s1 += v * v; sm += mv;
  }
  __shared__ float sh0[TPB], sh1[TPB], sh2[TPB];
  sh0[threadIdx.x] = s0; sh1[threadIdx.x] = s1; sh2[threadIdx.x] = sm;
  __syncthreads();
  for (int off = TPB / 2; off > 0; off >>= 1) {
    if (threadIdx.x < off) {
      sh0[threadIdx.x] += sh0[threadIdx.x + off];
      sh1[threadIdx.x] += sh1[threadIdx.x + off];
      sh2[threadIdx.x] += sh2[threadIdx.x + off];
    }
    __syncthreads();
  }
  if (threadIdx.x == 0) {
    const int S = gridDim.x;
    part[(c * S + s) * 2] = sh0[0];
    part[(c * S + s) * 2 + 1] = sh1[0];
    if (c == 0) partM[s] = sh2[0];
  }
}

__global__ __launch_bounds__(64) void k_stats2(const float* __restrict__ part,
                                               const float* __restrict__ partM,
                                               float* __restrict__ stats, int S) {
  const int c = blockIdx.x, t = threadIdx.x;
  float s0 = 0.f, s1 = 0.f, sm = 0.f;
  for (int s = t; s < S; s += 64) {
    s0 += part[(c * S + s) * 2];
    s1 += part[(c * S + s) * 2 + 1];
    sm += partM[s];
  }
  for (int off = 32; off > 0; off >>= 1) {
    s0 += __shfl_down(s0, off);
    s1 += __shfl_down(s1, off);
    sm += __shfl_down(sm, off);
  }
  if (t == 0) {
    float n = fmaxf(sm, 1.f);
    float mu = s0 / n;
    float var = fmaxf(s1 / n - mu * mu, 0.f);
    stats[2 * c] = mu;
    stats[2 * c + 1] = rsqrtf(var + 1e-5f);
  }
}

__global__ __launch_bounds__(TPB) void k_apply(float* __restrict__ a,
                                               const float* __restrict__ m,
                                               const float* __restrict__ stats,
                                               int vox, long total) {
  long idx = blockIdx.x * (long)TPB + threadIdx.x;
  if (idx >= total) return;
  int c = (int)(idx / vox);
  int p = (int)(idx % vox);
  float v = (a[idx] - stats[2 * c]) * stats[2 * c + 1];
  a[idx] = fmaxf(v, 0.f) * m[p];
}

__global__ __launch_bounds__(TPB) void k_apply_out(const float* __restrict__ a,
                                                   const float* __restrict__ m,
                                                   const float* __restrict__ stats,
                                                   float* __restrict__ out,
                                                   int vox, long total) {
  long idx = blockIdx.x * (long)TPB + threadIdx.x;
  if (idx >= total) return;
  int c = (int)(idx / vox);
  int p = (int)(idx % vox);
  float v = (a[idx] - stats[2 * c]) * stats[2 * c + 1];
  out[idx] = fmaxf(v, 0.f) * m[p];
}

// ================= workspace layout (floats) =================
constexpr long o_m0 = 0;
constexpr long o_m1 = 262144;
constexpr long o_m2 = 294912;
constexpr long o_m3 = 299008;
constexpr long o_m4 = 299520;
constexpr long o_m5 = 299584;
constexpr long o_st = 299592;
constexpr long o_A  = 301696;     // 2M: xm -> scratch -> u3 -> fin
constexpr long o_B  = 2398848;    // 2M: a0
constexpr long o_C  = 4496000;    // 512K: a1
constexpr long o_D  = 5020288;    // 128K: a2
constexpr long o_E  = 5151360;    // 32K: a3
constexpr long o_F  = 5184128;    // 8K: a4
constexpr long o_G  = 5192320;    // 8K: a5
constexpr long o_H  = 5200512;    // 32K: u0
constexpr long o_I  = 5233280;    // 32K: f0
constexpr long o_J  = 5266048;    // 128K: u1
constexpr long o_K  = 5397120;    // 128K: f1
constexpr long o_L  = 5528192;    // 512K: u2
constexpr long o_M  = 6052480;    // 512K: f2
constexpr long o_N  = 6576768;    // 2M: f3 (up3 scratch before fu3)
constexpr long o_P  = 8673920;    // BN partials
constexpr long o_PM = 8690304;
constexpr long o_S  = 8690368;    // tail scratch (size = ws_size/4 - o_S)
constexpr long o_fin = o_A;

extern "C" void kernel_launch(void* const* d_in, const int* in_sizes, int n_in,
                              void* d_out, int out_size, void* d_ws, size_t ws_size,
                              hipStream_t stream) {
  const float* x      = (const float*)d_in[0];
  const float* mask   = (const float*)d_in[1];
  const float* w_enc0 = (const float*)d_in[2];
  const float* w_enc1 = (const float*)d_in[3];
  const float* w_enc2 = (const float*)d_in[4];
  const float* w_enc3 = (const float*)d_in[5];
  const float* w_btd  = (const float*)d_in[6];
  const float* w_btc  = (const float*)d_in[7];
  const float* w_up0  = (const float*)d_in[8];
  const float* w_fu0  = (const float*)d_in[9];
  const float* w_up1  = (const float*)d_in[10];
  const float* w_fu1  = (const float*)d_in[11];
  const float* w_up2  = (const float*)d_in[12];
  const float* w_fu2  = (const float*)d_in[13];
  const float* w_up3  = (const float*)d_in[14];
  const float* w_fu3  = (const float*)d_in[15];
  const float* w_fin  = (const float*)d_in[16];

  float* ws = (float*)d_ws;
  float* st = ws + o_st;
  float* out = (float*)d_out;

  long tailCap = (long)(ws_size / 4) - o_S;
  if (tailCap < 0) tailCap = 0;

  auto blocks = [](long n) { return (unsigned)((n + TPB - 1) / TPB); };

  // masks
  k_mask0<<<blocks(262144), TPB, 0, stream>>>(mask, ws + o_m0, 262144);
  k_downmask<<<blocks(32768), TPB, 0, stream>>>(ws + o_m0, ws + o_m1, 32);
  k_downmask<<<blocks(4096), TPB, 0, stream>>>(ws + o_m1, ws + o_m2, 16);
  k_downmask<<<blocks(512), TPB, 0, stream>>>(ws + o_m2, ws + o_m3, 8);
  k_downmask<<<blocks(64), TPB, 0, stream>>>(ws + o_m3, ws + o_m4, 4);
  k_downmask<<<blocks(8), TPB, 0, stream>>>(ws + o_m4, ws + o_m5, 2);

  // masked input -> A
  k_maskx<<<blocks(8L * 262144), TPB, 0, stream>>>(x, ws + o_m0, ws + o_A,
                                                   8L * 262144, 262144);

  auto stats = [&](const float* a, const float* m, int C, int vox) {
    int S = vox / TPB; if (S < 1) S = 1; if (S > 64) S = 64;
    int chunk = vox / S;
    dim3 g(S, C);
    k_stats1<<<g, TPB, 0, stream>>>(a, m, ws + o_P, ws + o_PM, vox, chunk);
    k_stats2<<<C, 64, 0, stream>>>(ws + o_P, ws + o_PM, st, S);
  };
  auto bnrelu = [&](float* a, const float* m, int C, int vox) {
    stats(a, m, C, vox);
    long total = (long)C * vox;
    k_apply<<<blocks(total), TPB, 0, stream>>>(a, m, st, vox, total);
  };

#define GEMM(MT, MODE, A_, B1_, B2_, O_, M_, N_, K_, DIN_, DOUT_, C1_, Z_)   \
  do {                                                                        \
    int nch_ = ((K_) + 31) >> 5;                                              \
    int kper_ = (nch_ + (Z_) - 1) / (Z_);                                     \
    dim3 g_(((N_) + 63) / 64, (M_) / (MT), (Z_));                             \
    float* dst_ = ((Z_) > 1) ? (ws + o_A) : (O_);                             \
    k_gemm<MT, MODE><<<g_, TPB, 0, stream>>>(A_, B1_, B2_, dst_, M_, N_, K_,  \
                                             DIN_, DOUT_, C1_, kper_);        \
    if ((Z_) > 1)                                                             \
      k_sumparts<<<blocks((long)(M_) * (N_)), TPB, 0, stream>>>(              \
          ws + o_A, O_, (long)(M_) * (N_), (Z_));                             \
  } while (0)

  // merged convT: adaptive split-K depth; 1D grid + XCD-aware remap
  auto convTmerged = [&](const float* w, const float* in, float* o, int M,
                         int Cin, int Dh, int dMin, float* scrP, long scrPcap) {
    int lgDh = 31 - __builtin_clz(Dh);
    int Np = Dh * Dh * Dh;
    long unit = (long)M * Np;
    float* scr = scrP;
    long cap = scrPcap;
    if (tailCap > cap) { scr = ws + o_S; cap = tailCap; }
    int d = dMin, slices = 0;
    for (;;) {
      slices = 0;
      for (int c = 0; c < 8; c++) {
        int px = c & 1, py = (c >> 1) & 1, pz = (c >> 2) & 1;
        int T = 1 << ((1 - px) + (1 - py) + (1 - pz));
        int nch = (Cin * T) >> 5;
        slices += (nch + d - 1) / d;
      }
      if ((long)slices * unit <= cap || d >= 256) break;
      d <<= 1;
    }
    ParCfg pc;
    int acc = 0;
    for (int c = 0; c < 8; c++) {
      pc.zoff[c] = acc;
      int px = c & 1, py = (c >> 1) & 1, pz = (c >> 2) & 1;
      int T = 1 << ((1 - px) + (1 - py) + (1 - pz));
      int nch = (Cin * T) >> 5;
      pc.kper[c] = d;
      acc += (nch + d - 1) / d;
    }
    pc.zoff[8] = acc;
    int ntx = (Np + 63) / 64;
    int my = M / 64;
    int total = ntx * my * acc;
    k_gemmTm<<<dim3(total, 1, 1), TPB, 0, stream>>>(w, in, scr, M, Np, Cin, Dh,
                                                    pc, ntx, my);
    int lgNp = 3 * lgDh;
    int lgMN = lgNp + (31 - __builtin_clz(M));
    k_sumscatA<<<blocks(8L << lgMN), TPB, 0, stream>>>(scr, o, lgNp, lgMN,
                                                       Dh, lgDh, pc);
  };

  // N=8 weight-streaming GEMV, 4 rows/block (btd, btc), Z=4
  auto gemv8 = [&](const float* w, const float* in, float* o, int M, int Cin,
                   int Din, int mode, int Z) {
    int K = Cin * 27;
    float* bcol = ws + o_A;
    float* parts = ws + o_A + 262144;
    k_bcol8<<<blocks((long)K * 8), TPB, 0, stream>>>(in, bcol, K, Din, mode);
    int kq = K >> 2;
    int kqPer = (kq + Z - 1) / Z;
    dim3 g(M / 4, Z);
    k_gemv8d<<<g, TPB, 0, stream>>>(w, bcol, parts, M, K, kqPer);
    k_sumparts<<<blocks((long)M * 8), TPB, 0, stream>>>(parts, o, (long)M * 8, Z);
  };

  // ---------------- encoder ----------------
  GEMM(64, 0, w_enc0, ws + o_A, nullptr, ws + o_B, 64, 32768, 8 * 27, 64, 32, 0, 1);
  bnrelu(ws + o_B, ws + o_m1, 64, 32768);
  GEMM(64, 0, w_enc1, ws + o_B, nullptr, ws + o_C, 128, 4096, 64 * 27, 32, 16, 0, 4);
  bnrelu(ws + o_C, ws + o_m2, 128, 4096);
  GEMM(64, 0, w_enc2, ws + o_C, nullptr, ws + o_D, 256, 512, 128 * 27, 16, 8, 0, 16);
  bnrelu(ws + o_D, ws + o_m3, 256, 512);
  GEMM(64, 0, w_enc3, ws + o_D, nullptr, ws + o_E, 512, 64, 256 * 27, 8, 4, 0, 64);
  bnrelu(ws + o_E, ws + o_m4, 512, 64);

  // ---------------- bottleneck (4-row weight streamers, Z=4) ----------------
  gemv8(w_btd, ws + o_E, ws + o_F, 1024, 512, 4, 0, 4);
  bnrelu(ws + o_F, ws + o_m5, 1024, 8);
  gemv8(w_btc, ws + o_F, ws + o_G, 1024, 1024, 2, 3, 4);
  bnrelu(ws + o_G, ws + o_m5, 1024, 8);

  // ---------------- decoder ----------------
  // up0: compact parity GEMV (coalesced weight stream, read-once)
  {
    int K = 1024 * 27;
    float* bcol = ws + o_A;
    float* parts = ws + o_A + 262144;
    k_bcolT<<<blocks((long)K * 8), TPB, 0, stream>>>(ws + o_G, bcol, K);
    dim3 g(512, 4);
    k_gemvT64<<<g, TPB, 0, stream>>>(w_up0, bcol, parts, 512, 1024, 256);
    k_sumscatT<<<blocks(512L * 64), TPB, 0, stream>>>(parts, ws + o_H, 512, 4);
  }
  bnrelu(ws + o_H, ws + o_m4, 512, 64);
  GEMM(64, 2, w_fu0, ws + o_H, ws + o_E, ws + o_I, 512, 64, 1024, 4, 4, 512, 32);
  bnrelu(ws + o_I, ws + o_m4, 512, 64);

  convTmerged(w_up1, ws + o_I, ws + o_J, 256, 512, 4, 2, ws + o_A, 2097152);
  bnrelu(ws + o_J, ws + o_m3, 256, 512);
  GEMM(64, 2, w_fu1, ws + o_J, ws + o_D, ws + o_K, 256, 512, 512, 8, 8, 256, 16);
  bnrelu(ws + o_K, ws + o_m3, 256, 512);

  convTmerged(w_up2, ws + o_K, ws + o_L, 128, 256, 8, 2, ws + o_A, 2097152);
  bnrelu(ws + o_L, ws + o_m2, 128, 4096);
  GEMM(64, 2, w_fu2, ws + o_L, ws + o_C, ws + o_M, 128, 4096, 256, 16, 16, 128, 2);
  bnrelu(ws + o_M, ws + o_m2, 128, 4096);

  // up3: o_N scratch (8 slices, d=32) unless tail scratch allows deeper
  convTmerged(w_up3, ws + o_M, ws + o_A, 64, 128, 16, 4, ws + o_N, 2097152);
  bnrelu(ws + o_A, ws + o_m1, 64, 32768);
  GEMM(64, 2, w_fu3, ws + o_A, ws + o_B, ws + o_N, 64, 32768, 128, 32, 32, 64, 1);
  bnrelu(ws + o_N, ws + o_m1, 64, 32768);

  // ---------------- final up: per-column kernel, weights in LDS ----------
  {
    dim3 g(32768 / TPB, 1, 8);
    k_finup<<<g, TPB, 0, stream>>>(w_fin, ws + o_N, ws + o_fin);
  }
  {
    int vox = 262144, C = 16;
    int S = 64, chunk = vox / S;
    dim3 g(S, C);
    k_stats1<<<g, TPB, 0, stream>>>(ws + o_fin, ws + o_m0, ws + o_P, ws + o_PM,
                                    vox, chunk);
    k_stats2<<<C, 64, 0, stream>>>(ws + o_P, ws + o_PM, st, S);
    long total = (long)C * vox;
    k_apply_out<<<blocks(total), TPB, 0, stream>>>(ws + o_fin, ws + o_m0, st,
                                                   out, vox, total);
  }
#undef GEMM
}

// Round 23
// 754.511 us; speedup vs baseline: 1.0789x; 1.0789x over previous
//
#include <hip/hip_runtime.h>
#include <hip/hip_bf16.h>

#define TPB 256

struct ParCfg { int zoff[9]; int kper[8]; };

// ================= masks =================
__global__ __launch_bounds__(TPB) void k_mask0(const float* __restrict__ mask,
                                               float* __restrict__ m0, int n) {
  int i = blockIdx.x * TPB + threadIdx.x;
  if (i < n) m0[i] = (mask[i] < 0.1f) ? 1.0f : 0.0f;
}

__global__ __launch_bounds__(TPB) void k_downmask(const float* __restrict__ mi,
                                                  float* __restrict__ mo, int Dout) {
  int n = Dout * Dout * Dout;
  int idx = blockIdx.x * TPB + threadIdx.x;
  if (idx >= n) return;
  int Din = Dout * 2;
  int ox = idx % Dout, oy = (idx / Dout) % Dout, oz = idx / (Dout * Dout);
  float v = 0.f;
  for (int kz = 0; kz < 3; kz++) {
    int iz = 2 * oz + kz - 1; if ((unsigned)iz >= (unsigned)Din) continue;
    for (int ky = 0; ky < 3; ky++) {
      int iy = 2 * oy + ky - 1; if ((unsigned)iy >= (unsigned)Din) continue;
      for (int kx = 0; kx < 3; kx++) {
        int ix = 2 * ox + kx - 1; if ((unsigned)ix >= (unsigned)Din) continue;
        v = fmaxf(v, mi[(iz * Din + iy) * Din + ix]);
      }
    }
  }
  mo[idx] = v;
}

__global__ __launch_bounds__(TPB) void k_maskx(const float* __restrict__ x,
                                               const float* __restrict__ m,
                                               float* __restrict__ o,
                                               long total, int vox) {
  long i = blockIdx.x * (long)TPB + threadIdx.x;
  if (i < total) o[i] = x[i] * m[i % vox];
}

__global__ __launch_bounds__(TPB) void k_sumparts(const float* __restrict__ parts,
                                                  float* __restrict__ out,
                                                  long n, int s) {
  long i = blockIdx.x * (long)TPB + threadIdx.x;
  if (i >= n) return;
  float a = 0.f;
  for (int j = 0; j < s; j++) a += parts[(long)j * n + i];
  out[i] = a;
}

// all-classes sum+scatter for the merged convT kernel
__global__ __launch_bounds__(TPB) void k_sumscatA(const float* __restrict__ parts,
                                                  float* __restrict__ out,
                                                  int lgNp, int lgMN, int Dh,
                                                  int lgDh, ParCfg pc) {
  long idx = blockIdx.x * (long)TPB + threadIdx.x;
  if (idx >= (8L << lgMN)) return;
  int cls = (int)(idx >> lgMN);
  int r = (int)(idx & ((1L << lgMN) - 1));
  int co = r >> lgNp;
  int pp = r & ((1 << lgNp) - 1);
  float s = 0.f;
  for (int z = pc.zoff[cls]; z < pc.zoff[cls + 1]; z++)
    s += parts[((long)z << lgMN) + r];
  int px = cls & 1, py = (cls >> 1) & 1, pz = (cls >> 2) & 1;
  int ox = pp & (Dh - 1), oy = (pp >> lgDh) & (Dh - 1), oz = pp >> (2 * lgDh);
  int DF = Dh * 2;
  long fc = ((long)(2 * oz + pz) * DF + (2 * oy + py)) * DF + (2 * ox + px);
  out[(long)co * ((long)DF * DF * DF) + fc] = s;
}

// ================= N=8 weight-streaming path (btd, btc) =================
__global__ __launch_bounds__(TPB) void k_bcol8(const float* __restrict__ in,
                                               float* __restrict__ Bcol,
                                               int K, int Din, int mode) {
  long idx = blockIdx.x * (long)TPB + threadIdx.x;
  if (idx >= (long)K * 8) return;
  int kg = (int)(idx >> 3), pp = (int)(idx & 7);
  int ci = kg / 27, tap = kg - ci * 27;
  int kz = tap / 9, r9 = tap - kz * 9;
  int ky = r9 / 3, kx = r9 - ky * 3;
  int oz = pp >> 2, oy = (pp >> 1) & 1, ox = pp & 1;
  int iz, iy, ix;
  if (mode == 0) { iz = 2 * oz + kz - 1; iy = 2 * oy + ky - 1; ix = 2 * ox + kx - 1; }
  else           { iz = oz + kz - 1;     iy = oy + ky - 1;     ix = ox + kx - 1; }
  float v = 0.f;
  if ((unsigned)iz < (unsigned)Din && (unsigned)iy < (unsigned)Din &&
      (unsigned)ix < (unsigned)Din)
    v = in[(long)ci * Din * Din * Din + ((long)iz * Din + iy) * Din + ix];
  Bcol[idx] = v;
}

// 4 rows per block: every Bcol load amortized over 4 weight rows.
__global__ __launch_bounds__(TPB) void k_gemv8d(const float* __restrict__ W,
                                                const float* __restrict__ Bcol,
                                                float* __restrict__ part,
                                                int M, int K, int kqPer) {
  const int t = threadIdx.x;
  const int co0 = blockIdx.x * 4;
  const int kq = K >> 2;
  int q0 = blockIdx.y * kqPer;
  int q1 = q0 + kqPer; if (q1 > kq) q1 = kq;
  float acc[4][8];
#pragma unroll
  for (int r = 0; r < 4; r++)
#pragma unroll
    for (int p = 0; p < 8; p++) acc[r][p] = 0.f;
  const float4* W4 = (const float4*)W;
  for (int i = q0 + t; i < q1; i += TPB) {
    float4 w4[4];
#pragma unroll
    for (int r = 0; r < 4; r++) w4[r] = W4[(long)(co0 + r) * kq + i];
    const float* bp = &Bcol[(long)i * 32];
#pragma unroll
    for (int j = 0; j < 4; j++) {
      const float4 b0 = *(const float4*)&bp[j * 8];
      const float4 b1 = *(const float4*)&bp[j * 8 + 4];
#pragma unroll
      for (int r = 0; r < 4; r++) {
        const float w = (j == 0) ? w4[r].x : (j == 1) ? w4[r].y
                        : (j == 2) ? w4[r].z : w4[r].w;
        acc[r][0] += w * b0.x; acc[r][1] += w * b0.y;
        acc[r][2] += w * b0.z; acc[r][3] += w * b0.w;
        acc[r][4] += w * b1.x; acc[r][5] += w * b1.y;
        acc[r][6] += w * b1.z; acc[r][7] += w * b1.w;
      }
    }
  }
#pragma unroll
  for (int off = 32; off > 0; off >>= 1)
#pragma unroll
    for (int r = 0; r < 4; r++)
#pragma unroll
      for (int p = 0; p < 8; p++) acc[r][p] += __shfl_down(acc[r][p], off);
  __shared__ float Rs[4][4][8];
  if ((t & 63) == 0) {
#pragma unroll
    for (int r = 0; r < 4; r++)
#pragma unroll
      for (int p = 0; p < 8; p++) Rs[t >> 6][r][p] = acc[r][p];
  }
  __syncthreads();
  if (t < 32) {
    int r = t >> 3, p = t & 7;
    part[((long)blockIdx.y * M + co0 + r) * 8 + p] =
        Rs[0][r][p] + Rs[1][r][p] + Rs[2][r][p] + Rs[3][r][p];
  }
}

// ============ up0: dense parity im2colT, Bcol64[K][64] ============
// column q = cls*8 + p; nonzero only when tap's parity class == cls.
// ix = oxh + cx - 1, cx = (kx + (kx&1))>>1  (verified compact rule)
__global__ __launch_bounds__(TPB) void k_bcolT64(const float* __restrict__ in,
                                                 float* __restrict__ B, int K) {
  long idx = blockIdx.x * (long)TPB + threadIdx.x;
  if (idx >= (long)K * 64) return;
  int kg = (int)(idx >> 6), q = (int)(idx & 63);
  int ci = kg / 27, tap = kg - ci * 27;
  int kz = tap / 9, r9 = tap - kz * 9;
  int ky = r9 / 3, kx = r9 - ky * 3;
  int clsT = ((kz & 1) << 2) | ((ky & 1) << 1) | (kx & 1);
  int cls = q >> 3, p = q & 7;
  float v = 0.f;
  if (cls == clsT) {
    int oxh = p & 1, oyh = (p >> 1) & 1, ozh = p >> 2;
    int cx = (kx + (kx & 1)) >> 1;
    int cy = (ky + (ky & 1)) >> 1;
    int cz = (kz + (kz & 1)) >> 1;
    int ix = oxh + cx - 1, iy = oyh + cy - 1, iz = ozh + cz - 1;
    if ((unsigned)ix < 2u && (unsigned)iy < 2u && (unsigned)iz < 2u)
      v = in[(long)ci * 8 + (iz * 2 + iy) * 2 + ix];
  }
  B[idx] = v;
}

// sum split-K partials and scatter [cls][p] -> strided 4^3 grid
__global__ __launch_bounds__(TPB) void k_sumscatT(const float* __restrict__ parts,
                                                  float* __restrict__ out,
                                                  int M, int Z) {
  long idx = blockIdx.x * (long)TPB + threadIdx.x;
  if (idx >= (long)M * 64) return;
  int row = (int)(idx >> 6), q = (int)(idx & 63);
  float s = 0.f;
  for (int z = 0; z < Z; z++) s += parts[((long)z * M + row) * 64 + q];
  int cls = q >> 3, p = q & 7;
  int px = cls & 1, py = (cls >> 1) & 1, pz = (cls >> 2) & 1;
  int oxh = p & 1, oyh = (p >> 1) & 1, ozh = p >> 2;
  int fc = (2 * ozh + pz) * 16 + (2 * oyh + py) * 4 + (2 * oxh + px);
  out[(long)row * 64 + fc] = s;
}

// ================= tiled implicit-GEMM, split-K, reg-prefetch =================
// MODE 0: conv k3 s2 p1   MODE 2: 1x1 concat-fuse / dense B   MODE 3: conv k3 s1 p1
template<int MT, int MODE>
__global__ __launch_bounds__(TPB) void k_gemm(const float* __restrict__ A,
                                              const float* __restrict__ B1,
                                              const float* __restrict__ B2,
                                              float* __restrict__ C,
                                              int M, int N, int K,
                                              int Din, int Dout, int C1,
                                              int kcPer) {
  constexpr int MR = MT / 16;
  constexpr int AEL = (MT == 64) ? 8 : 2;
  __shared__ __align__(16) float At[32][MT];
  __shared__ __align__(16) float Bt[32][64];

  const int t = threadIdx.x;
  const int n0 = blockIdx.x * 64;
  const int m0 = blockIdx.y * MT;

  const int p0 = (t & 15) * 4;
  const int co0 = (t >> 4) * MR;

  const int pb = t & 63;
  const int kb0 = (t >> 6) * 8;
  const int pp = n0 + pb;
  const int oxb = pp & (Dout - 1);
  const int oyb = (pp / Dout) & (Dout - 1);
  const int ozb = pp / (Dout * Dout);

  const int nch = (K + 31) >> 5;
  const int c0 = blockIdx.z * kcPer;
  int c1 = c0 + kcPer; if (c1 > nch) c1 = nch;

  float acc[MR][4];
#pragma unroll
  for (int a = 0; a < MR; a++)
#pragma unroll
    for (int b = 0; b < 4; b++) acc[a][b] = 0.f;

  float raf[AEL];
  float rb[8];
  const int co_a = (MT == 64) ? (t >> 2) : (t & 15);
  const int ka   = (MT == 64) ? ((t & 3) * 8) : ((t >> 4) * 2);
  const long arow = (long)(m0 + co_a) * K;

  auto loadA = [&](int c) {
    const int k0 = c << 5;
    if (MT == 64) {
#pragma unroll
      for (int j = 0; j < 2; j++) {
        const int kg = k0 + ka + j * 4;
        float4 v = (kg < K) ? *(const float4*)&A[arow + kg]
                            : make_float4(0.f, 0.f, 0.f, 0.f);
        raf[j * 4 + 0] = v.x; raf[j * 4 + 1] = v.y;
        raf[j * 4 + 2] = v.z; raf[j * 4 + 3] = v.w;
      }
    } else {
      const int kg = k0 + ka;
      raf[0] = (kg < K) ? A[arow + kg] : 0.f;
      raf[1] = (kg + 1 < K) ? A[arow + kg + 1] : 0.f;
    }
  };

  auto loadB = [&](int c) {
    const int k0 = c << 5;
#pragma unroll
    for (int j = 0; j < 8; j++) {
      const int kg = k0 + kb0 + j;
      float v = 0.f;
      if (kg < K && pp < N) {
        if (MODE == 2) {
          v = (kg < C1) ? B1[(long)kg * N + pp] : B2[(long)(kg - C1) * N + pp];
        } else {
          const int ci = kg / 27;
          const int tap = kg - ci * 27;
          const int kz = tap / 9;
          const int r9 = tap - kz * 9;
          const int ky = r9 / 3;
          const int kx = r9 - ky * 3;
          int iz, iy, ix;
          bool ok;
          if (MODE == 0) {
            iz = 2 * ozb + kz - 1; iy = 2 * oyb + ky - 1; ix = 2 * oxb + kx - 1;
            ok = (unsigned)iz < (unsigned)Din && (unsigned)iy < (unsigned)Din &&
                 (unsigned)ix < (unsigned)Din;
          } else { // MODE 3
            iz = ozb + kz - 1; iy = oyb + ky - 1; ix = oxb + kx - 1;
            ok = (unsigned)iz < (unsigned)Din && (unsigned)iy < (unsigned)Din &&
                 (unsigned)ix < (unsigned)Din;
          }
          if (ok)
            v = B1[(long)ci * Din * Din * Din + ((long)iz * Din + iy) * Din + ix];
        }
      }
      rb[j] = v;
    }
  };

  if (c0 < c1) { loadA(c0); loadB(c0); }

  for (int c = c0; c < c1; ++c) {
    __syncthreads();
#pragma unroll
    for (int j = 0; j < AEL; j++) At[ka + j][co_a] = raf[j];
#pragma unroll
    for (int j = 0; j < 8; j++) Bt[kb0 + j][pb] = rb[j];
    if (c + 1 < c1) { loadA(c + 1); loadB(c + 1); }
    __syncthreads();
#pragma unroll
    for (int kk = 0; kk < 32; ++kk) {
      const float4 b4 = *(const float4*)&Bt[kk][p0];
      if (MR == 4) {
        const float4 a4 = *(const float4*)&At[kk][co0];
        acc[0][0] += a4.x * b4.x; acc[0][1] += a4.x * b4.y;
        acc[0][2] += a4.x * b4.z; acc[0][3] += a4.x * b4.w;
        acc[1][0] += a4.y * b4.x; acc[1][1] += a4.y * b4.y;
        acc[1][2] += a4.y * b4.z; acc[1][3] += a4.y * b4.w;
        acc[2][0] += a4.z * b4.x; acc[2][1] += a4.z * b4.y;
        acc[2][2] += a4.z * b4.z; acc[2][3] += a4.z * b4.w;
        acc[3][0] += a4.w * b4.x; acc[3][1] += a4.w * b4.y;
        acc[3][2] += a4.w * b4.z; acc[3][3] += a4.w * b4.w;
      } else {
        const float a = At[kk][co0];
        acc[0][0] += a * b4.x; acc[0][1] += a * b4.y;
        acc[0][2] += a * b4.z; acc[0][3] += a * b4.w;
      }
    }
  }

  float* Cz = C + (long)blockIdx.z * ((long)M * N);
#pragma unroll
  for (int mr = 0; mr < MR; mr++) {
    if (n0 + p0 < N) {
      float4 v = make_float4(acc[mr][0], acc[mr][1], acc[mr][2], acc[mr][3]);
      *(float4*)&Cz[(long)(m0 + co0 + mr) * N + n0 + p0] = v;
    }
  }
}

// ================= merged convT-parity GEMM (up1..up3), 3D grid ============
__global__ __launch_bounds__(TPB) void k_gemmTm(const float* __restrict__ A,
                                                const float* __restrict__ B1,
                                                float* __restrict__ C,
                                                int M, int N, int Cin, int Din,
                                                ParCfg pc) {
  __shared__ __align__(16) float At[32][64];
  __shared__ __align__(16) float Bt[32][64];

  const int t = threadIdx.x;
  const int n0 = blockIdx.x * 64;
  const int m0 = blockIdx.y * 64;
  const int z = blockIdx.z;

  int cls = 0;
#pragma unroll
  for (int c = 1; c < 8; c++) if (z >= pc.zoff[c]) cls = c;
  const int zi = z - pc.zoff[cls];
  const int kperc = pc.kper[cls];

  const int px = cls & 1, py = (cls >> 1) & 1, pz = (cls >> 2) & 1;
  const int lgnx = 1 - px, lgny = 1 - py;
  const int lgT = lgnx + lgny + (1 - pz);
  const int T = 1 << lgT;
  const int K = Cin << lgT;
  const int nch = K >> 5;

  const int p0 = (t & 15) * 4;
  const int co0 = (t >> 4) * 4;
  const int pb = t & 63;
  const int kb0 = (t >> 6) * 8;      // wave-uniform
  const int pp = n0 + pb;
  const int oxb = pp & (Din - 1);
  const int oyb = (pp / Din) & (Din - 1);
  const int ozb = pp / (Din * Din);
  const long vin = (long)Din * Din * Din;

  const int bz = ozb - 1 + pz, by = oyb - 1 + py, bx = oxb - 1 + px;
  const long laneOff = (long)bz * Din * Din + (long)by * Din + bx;
  unsigned vmask = 0;
  if (pp < N) {
    int nz_ = pz ? 1 : 2, ny_ = py ? 1 : 2, nx_ = px ? 1 : 2;
    for (int tz = 0; tz < nz_; tz++)
      for (int ty = 0; ty < ny_; ty++)
        for (int tx = 0; tx < nx_; tx++) {
          bool ok = (unsigned)(bz + tz) < (unsigned)Din &&
                    (unsigned)(by + ty) < (unsigned)Din &&
                    (unsigned)(bx + tx) < (unsigned)Din;
          if (ok) vmask |= 1u << ((tz << (lgny + lgnx)) | (ty << lgnx) | tx);
        }
  }

  const int c0 = zi * kperc;
  int c1 = c0 + kperc; if (c1 > nch) c1 = nch;

  float acc[4][4];
#pragma unroll
  for (int a = 0; a < 4; a++)
#pragma unroll
    for (int b = 0; b < 4; b++) acc[a][b] = 0.f;

  float raf[8];
  float rb[8];
  const int co_a = t & 63;
  const int ka   = (t >> 6) * 8;
  const long abase = (long)(m0 + co_a) * Cin * 27;

  auto loadA = [&](int c) {
    const int k0 = c << 5;
#pragma unroll
    for (int j = 0; j < 8; j++) {
      const int kg = k0 + ka + j;
      float v = 0.f;
      if (kg < K) {
        int ci = kg >> lgT;
        int tt = kg & (T - 1);
        int tx = tt & ((1 << lgnx) - 1);
        int r = tt >> lgnx;
        int ty = r & ((1 << lgny) - 1);
        int tz = r >> lgny;
        int kx = px ? 1 : (tx << 1);
        int ky = py ? 1 : (ty << 1);
        int kz = pz ? 1 : (tz << 1);
        v = A[abase + ci * 27 + (kz * 3 + ky) * 3 + kx];
      }
      raf[j] = v;
    }
  };

  auto loadB = [&](int c) {
    const int k0 = c << 5;
#pragma unroll
    for (int j = 0; j < 8; j++) {
      const int kg = k0 + kb0 + j;
      float v = 0.f;
      if (kg < K) {
        int ci = kg >> lgT;
        int tt = kg & (T - 1);
        int tx = tt & ((1 << lgnx) - 1);
        int r = tt >> lgnx;
        int ty = r & ((1 << lgny) - 1);
        int tz = r >> lgny;
        long base = (long)ci * vin + (long)tz * Din * Din + ty * Din + tx;
        if ((vmask >> tt) & 1) v = B1[base + laneOff];
      }
      rb[j] = v;
    }
  };

  if (c0 < c1) { loadA(c0); loadB(c0); }

  for (int c = c0; c < c1; ++c) {
    __syncthreads();
#pragma unroll
    for (int j = 0; j < 8; j++) At[ka + j][co_a] = raf[j];
#pragma unroll
    for (int j = 0; j < 8; j++) Bt[kb0 + j][pb] = rb[j];
    if (c + 1 < c1) { loadA(c + 1); loadB(c + 1); }
    __syncthreads();
#pragma unroll
    for (int kk = 0; kk < 32; ++kk) {
      const float4 b4 = *(const float4*)&Bt[kk][p0];
      const float4 a4 = *(const float4*)&At[kk][co0];
      acc[0][0] += a4.x * b4.x; acc[0][1] += a4.x * b4.y;
      acc[0][2] += a4.x * b4.z; acc[0][3] += a4.x * b4.w;
      acc[1][0] += a4.y * b4.x; acc[1][1] += a4.y * b4.y;
      acc[1][2] += a4.y * b4.z; acc[1][3] += a4.y * b4.w;
      acc[2][0] += a4.z * b4.x; acc[2][1] += a4.z * b4.y;
      acc[2][2] += a4.z * b4.z; acc[2][3] += a4.z * b4.w;
      acc[3][0] += a4.w * b4.x; acc[3][1] += a4.w * b4.y;
      acc[3][2] += a4.w * b4.z; acc[3][3] += a4.w * b4.w;
    }
  }

  float* Cz = C + (long)z * ((long)M * N);
#pragma unroll
  for (int mr = 0; mr < 4; mr++) {
    if (n0 + p0 < N) {
      float4 v = make_float4(acc[mr][0], acc[mr][1], acc[mr][2], acc[mr][3]);
      *(float4*)&Cz[(long)(m0 + co0 + mr) * N + n0 + p0] = v;
    }
  }
}

// ================= final-up: M=16, per-column kernel, reg-prefetch ==========
__global__ __launch_bounds__(TPB) void k_finup(const float* __restrict__ A,
                                               const float* __restrict__ B1,
                                               float* __restrict__ C) {
  __shared__ __align__(16) float Ws[8192];
  const int cls = blockIdx.z;
  const int px = cls & 1, py = (cls >> 1) & 1, pz = (cls >> 2) & 1;
  const int lgnx = 1 - px, lgny = 1 - py;
  const int lgT = lgnx + lgny + (1 - pz);
  const int T = 1 << lgT;
  const int K = 64 << lgT;

  for (int idx = threadIdx.x; idx < K * 16; idx += TPB) {
    int k = idx >> 4, co = idx & 15;
    int ci = k >> lgT;
    int tt = k & (T - 1);
    int tx = tt & ((1 << lgnx) - 1);
    int r = tt >> lgnx;
    int ty = r & ((1 << lgny) - 1);
    int tz = r >> lgny;
    int kx = px ? 1 : (tx << 1);
    int ky = py ? 1 : (ty << 1);
    int kz = pz ? 1 : (tz << 1);
    Ws[idx] = A[((long)co * 64 + ci) * 27 + (kz * 3 + ky) * 3 + kx];
  }

  const int pp = blockIdx.x * TPB + threadIdx.x;
  const int oxb = pp & 31, oyb = (pp >> 5) & 31, ozb = pp >> 10;
  const int bz = ozb - 1 + pz, by = oyb - 1 + py, bx = oxb - 1 + px;
  const long laneOff = (long)bz * 1024 + by * 32 + bx;
  unsigned vmask = 0;
  {
    int nz_ = pz ? 1 : 2, ny_ = py ? 1 : 2, nx_ = px ? 1 : 2;
    for (int tz = 0; tz < nz_; tz++)
      for (int ty = 0; ty < ny_; ty++)
        for (int tx = 0; tx < nx_; tx++) {
          bool ok = (unsigned)(bz + tz) < 32u && (unsigned)(by + ty) < 32u &&
                    (unsigned)(bx + tx) < 32u;
          if (ok) vmask |= 1u << ((tz << (lgny + lgnx)) | (ty << lgnx) | tx);
        }
  }

  int toff[8];
#pragma unroll
  for (int tt = 0; tt < 8; tt++) {
    int tx = tt & ((1 << lgnx) - 1);
    int r = tt >> lgnx;
    int ty = r & ((1 << lgny) - 1);
    int tz = r >> lgny;
    toff[tt] = tz * 1024 + ty * 32 + tx;
  }
  __syncthreads();

  float acc[16];
#pragma unroll
  for (int co = 0; co < 16; co++) acc[co] = 0.f;

  float bcur[8], bnxt[8];
  auto loadG = [&](int ci, float (&bv)[8]) {
#pragma unroll
    for (int tt = 0; tt < 8; tt++) {
      if (tt < T)
        bv[tt] = ((vmask >> tt) & 1)
                     ? B1[(long)ci * 32768 + toff[tt] + laneOff] : 0.f;
      else
        bv[tt] = 0.f;
    }
  };

  loadG(0, bcur);
  for (int ci = 0; ci < 64; ci++) {
    if (ci + 1 < 64) loadG(ci + 1, bnxt);
#pragma unroll
    for (int tt = 0; tt < 8; tt++) {
      if (tt < T) {
        const float b = bcur[tt];
        const float4* wp = (const float4*)&Ws[((ci << lgT) + tt) * 16];
#pragma unroll
        for (int q = 0; q < 4; q++) {
          float4 w = wp[q];
          acc[q * 4 + 0] += w.x * b;
          acc[q * 4 + 1] += w.y * b;
          acc[q * 4 + 2] += w.z * b;
          acc[q * 4 + 3] += w.w * b;
        }
      }
    }
#pragma unroll
    for (int tt = 0; tt < 8; tt++) bcur[tt] = bnxt[tt];
  }

  const long fc = ((long)(2 * ozb + pz) * 64 + (2 * oyb + py)) * 64 +
                  (2 * oxb + px);
#pragma unroll
  for (int co = 0; co < 16; co++) C[(long)co * 262144 + fc] = acc[co];
}

// ================= hierarchical masked BN stats =================
__global__ __launch_bounds__(TPB) void k_stats1(const float* __restrict__ a,
                                                const float* __restrict__ m,
                                                float* __restrict__ part,
                                                float* __restrict__ partM,
                                                int vox, int chunk) {
  const int s = blockIdx.x, c = blockIdx.y;
  const float* ap = a + (long)c * vox + (long)s * chunk;
  const float* mp = m + (long)s * chunk;
  float s0 = 0.f, s1 = 0.f, sm = 0.f;
  for (int i = threadIdx.x; i < chunk; i += TPB) {
    float mv = mp[i];
    float v = ap[i] * mv;
    s0 += v; s1 += v * v; sm += mv;
  }
  __shared__ float sh0[TPB], sh1[TPB], sh2[TPB];
  sh0[threadIdx.x] = s0; sh1[threadIdx.x] = s1; sh2[threadIdx.x] = sm;
  __syncthreads();
  for (int off = TPB / 2; off > 0; off >>= 1) {
    if (threadIdx.x < off) {
      sh0[threadIdx.x] += sh0[threadIdx.x + off];
      sh1[threadIdx.x] += sh1[threadIdx.x + off];
      sh2[threadIdx.x] += sh2[threadIdx.x + off];
    }
    __syncthreads();
  }
  if (threadIdx.x == 0) {
    const int S = gridDim.x;
    part[(c * S + s) * 2] = sh0[0];
    part[(c * S + s) * 2 + 1] = sh1[0];
    if (c == 0) partM[s] = sh2[0];
  }
}

__global__ __launch_bounds__(64) void k_stats2(const float* __restrict__ part,
                                               const float* __restrict__ partM,
                                               float* __restrict__ stats, int S) {
  const int c = blockIdx.x, t = threadIdx.x;
  float s0 = 0.f, s1 = 0.f, sm = 0.f;
  for (int s = t; s < S; s += 64) {
    s0 += part[(c * S + s) * 2];
    s1 += part[(c * S + s) * 2 + 1];
    sm += partM[s];
  }
  for (int off = 32; off > 0; off >>= 1) {
    s0 += __shfl_down(s0, off);
    s1 += __shfl_down(s1, off);
    sm += __shfl_down(sm, off);
  }
  if (t == 0) {
    float n = fmaxf(sm, 1.f);
    float mu = s0 / n;
    float var = fmaxf(s1 / n - mu * mu, 0.f);
    stats[2 * c] = mu;
    stats[2 * c + 1] = rsqrtf(var + 1e-5f);
  }
}

__global__ __launch_bounds__(TPB) void k_apply(float* __restrict__ a,
                                               const float* __restrict__ m,
                                               const float* __restrict__ stats,
                                               int vox, long total) {
  long idx = blockIdx.x * (long)TPB + threadIdx.x;
  if (idx >= total) return;
  int c = (int)(idx / vox);
  int p = (int)(idx % vox);
  float v = (a[idx] - stats[2 * c]) * stats[2 * c + 1];
  a[idx] = fmaxf(v, 0.f) * m[p];
}

__global__ __launch_bounds__(TPB) void k_apply_out(const float* __restrict__ a,
                                                   const float* __restrict__ m,
                                                   const float* __restrict__ stats,
                                                   float* __restrict__ out,
                                                   int vox, long total) {
  long idx = blockIdx.x * (long)TPB + threadIdx.x;
  if (idx >= total) return;
  int c = (int)(idx / vox);
  int p = (int)(idx % vox);
  float v = (a[idx] - stats[2 * c]) * stats[2 * c + 1];
  out[idx] = fmaxf(v, 0.f) * m[p];
}

// ================= workspace layout (floats) =================
constexpr long o_m0 = 0;
constexpr long o_m1 = 262144;
constexpr long o_m2 = 294912;
constexpr long o_m3 = 299008;
constexpr long o_m4 = 299520;
constexpr long o_m5 = 299584;
constexpr long o_st = 299592;
constexpr long o_A  = 301696;     // 2M: xm -> scratch -> u3 -> fin
constexpr long o_B  = 2398848;    // 2M: a0
constexpr long o_C  = 4496000;    // 512K: a1
constexpr long o_D  = 5020288;    // 128K: a2
constexpr long o_E  = 5151360;    // 32K: a3
constexpr long o_F  = 5184128;    // 8K: a4
constexpr long o_G  = 5192320;    // 8K: a5
constexpr long o_H  = 5200512;    // 32K: u0
constexpr long o_I  = 5233280;    // 32K: f0
constexpr long o_J  = 5266048;    // 128K: u1
constexpr long o_K  = 5397120;    // 128K: f1
constexpr long o_L  = 5528192;    // 512K: u2
constexpr long o_M  = 6052480;    // 512K: f2
constexpr long o_N  = 6576768;    // 2M: f3 (up0/up3 scratch before fu3)
constexpr long o_P  = 8673920;    // BN partials
constexpr long o_PM = 8690304;
constexpr long o_S  = 8690368;    // tail scratch (size = ws_size/4 - o_S)
constexpr long o_fin = o_A;

extern "C" void kernel_launch(void* const* d_in, const int* in_sizes, int n_in,
                              void* d_out, int out_size, void* d_ws, size_t ws_size,
                              hipStream_t stream) {
  const float* x      = (const float*)d_in[0];
  const float* mask   = (const float*)d_in[1];
  const float* w_enc0 = (const float*)d_in[2];
  const float* w_enc1 = (const float*)d_in[3];
  const float* w_enc2 = (const float*)d_in[4];
  const float* w_enc3 = (const float*)d_in[5];
  const float* w_btd  = (const float*)d_in[6];
  const float* w_btc  = (const float*)d_in[7];
  const float* w_up0  = (const float*)d_in[8];
  const float* w_fu0  = (const float*)d_in[9];
  const float* w_up1  = (const float*)d_in[10];
  const float* w_fu1  = (const float*)d_in[11];
  const float* w_up2  = (const float*)d_in[12];
  const float* w_fu2  = (const float*)d_in[13];
  const float* w_up3  = (const float*)d_in[14];
  const float* w_fu3  = (const float*)d_in[15];
  const float* w_fin  = (const float*)d_in[16];

  float* ws = (float*)d_ws;
  float* st = ws + o_st;
  float* out = (float*)d_out;

  long tailCap = (long)(ws_size / 4) - o_S;
  if (tailCap < 0) tailCap = 0;

  auto blocks = [](long n) { return (unsigned)((n + TPB - 1) / TPB); };

  // masks
  k_mask0<<<blocks(262144), TPB, 0, stream>>>(mask, ws + o_m0, 262144);
  k_downmask<<<blocks(32768), TPB, 0, stream>>>(ws + o_m0, ws + o_m1, 32);
  k_downmask<<<blocks(4096), TPB, 0, stream>>>(ws + o_m1, ws + o_m2, 16);
  k_downmask<<<blocks(512), TPB, 0, stream>>>(ws + o_m2, ws + o_m3, 8);
  k_downmask<<<blocks(64), TPB, 0, stream>>>(ws + o_m3, ws + o_m4, 4);
  k_downmask<<<blocks(8), TPB, 0, stream>>>(ws + o_m4, ws + o_m5, 2);

  // masked input -> A
  k_maskx<<<blocks(8L * 262144), TPB, 0, stream>>>(x, ws + o_m0, ws + o_A,
                                                   8L * 262144, 262144);

  auto stats = [&](const float* a, const float* m, int C, int vox) {
    int S = vox / TPB; if (S < 1) S = 1; if (S > 64) S = 64;
    int chunk = vox / S;
    dim3 g(S, C);
    k_stats1<<<g, TPB, 0, stream>>>(a, m, ws + o_P, ws + o_PM, vox, chunk);
    k_stats2<<<C, 64, 0, stream>>>(ws + o_P, ws + o_PM, st, S);
  };
  auto bnrelu = [&](float* a, const float* m, int C, int vox) {
    stats(a, m, C, vox);
    long total = (long)C * vox;
    k_apply<<<blocks(total), TPB, 0, stream>>>(a, m, st, vox, total);
  };

#define GEMM(MT, MODE, A_, B1_, B2_, O_, M_, N_, K_, DIN_, DOUT_, C1_, Z_)   \
  do {                                                                        \
    int nch_ = ((K_) + 31) >> 5;                                              \
    int kper_ = (nch_ + (Z_) - 1) / (Z_);                                     \
    dim3 g_(((N_) + 63) / 64, (M_) / (MT), (Z_));                             \
    float* dst_ = ((Z_) > 1) ? (ws + o_A) : (O_);                             \
    k_gemm<MT, MODE><<<g_, TPB, 0, stream>>>(A_, B1_, B2_, dst_, M_, N_, K_,  \
                                             DIN_, DOUT_, C1_, kper_);        \
    if ((Z_) > 1)                                                             \
      k_sumparts<<<blocks((long)(M_) * (N_)), TPB, 0, stream>>>(              \
          ws + o_A, O_, (long)(M_) * (N_), (Z_));                             \
  } while (0)

  // merged convT: adaptive split-K depth (3D grid, no remap)
  auto convTmerged = [&](const float* w, const float* in, float* o, int M,
                         int Cin, int Dh, int dMin, float* scrP, long scrPcap) {
    int lgDh = 31 - __builtin_clz(Dh);
    int Np = Dh * Dh * Dh;
    long unit = (long)M * Np;
    float* scr = scrP;
    long cap = scrPcap;
    if (tailCap > cap) { scr = ws + o_S; cap = tailCap; }
    int d = dMin, slices = 0;
    for (;;) {
      slices = 0;
      for (int c = 0; c < 8; c++) {
        int px = c & 1, py = (c >> 1) & 1, pz = (c >> 2) & 1;
        int T = 1 << ((1 - px) + (1 - py) + (1 - pz));
        int nch = (Cin * T) >> 5;
        slices += (nch + d - 1) / d;
      }
      if ((long)slices * unit <= cap || d >= 256) break;
      d <<= 1;
    }
    ParCfg pc;
    int acc = 0;
    for (int c = 0; c < 8; c++) {
      pc.zoff[c] = acc;
      int px = c & 1, py = (c >> 1) & 1, pz = (c >> 2) & 1;
      int T = 1 << ((1 - px) + (1 - py) + (1 - pz));
      int nch = (Cin * T) >> 5;
      pc.kper[c] = d;
      acc += (nch + d - 1) / d;
    }
    pc.zoff[8] = acc;
    dim3 g((Np + 63) / 64, M / 64, acc);
    k_gemmTm<<<g, TPB, 0, stream>>>(w, in, scr, M, Np, Cin, Dh, pc);
    int lgNp = 3 * lgDh;
    int lgMN = lgNp + (31 - __builtin_clz(M));
    k_sumscatA<<<blocks(8L << lgMN), TPB, 0, stream>>>(scr, o, lgNp, lgMN,
                                                       Dh, lgDh, pc);
  };

  // N=8 weight-streaming GEMV, 4 rows/block (btd, btc), Z=4
  auto gemv8 = [&](const float* w, const float* in, float* o, int M, int Cin,
                   int Din, int mode, int Z) {
    int K = Cin * 27;
    float* bcol = ws + o_A;
    float* parts = ws + o_A + 262144;
    k_bcol8<<<blocks((long)K * 8), TPB, 0, stream>>>(in, bcol, K, Din, mode);
    int kq = K >> 2;
    int kqPer = (kq + Z - 1) / Z;
    dim3 g(M / 4, Z);
    k_gemv8d<<<g, TPB, 0, stream>>>(w, bcol, parts, M, K, kqPer);
    k_sumparts<<<blocks((long)M * 8), TPB, 0, stream>>>(parts, o, (long)M * 8, Z);
  };

  // ---------------- encoder ----------------
  GEMM(64, 0, w_enc0, ws + o_A, nullptr, ws + o_B, 64, 32768, 8 * 27, 64, 32, 0, 1);
  bnrelu(ws + o_B, ws + o_m1, 64, 32768);
  GEMM(64, 0, w_enc1, ws + o_B, nullptr, ws + o_C, 128, 4096, 64 * 27, 32, 16, 0, 4);
  bnrelu(ws + o_C, ws + o_m2, 128, 4096);
  GEMM(64, 0, w_enc2, ws + o_C, nullptr, ws + o_D, 256, 512, 128 * 27, 16, 8, 0, 16);
  bnrelu(ws + o_D, ws + o_m3, 256, 512);
  GEMM(64, 0, w_enc3, ws + o_D, nullptr, ws + o_E, 512, 64, 256 * 27, 8, 4, 0, 64);
  bnrelu(ws + o_E, ws + o_m4, 512, 64);

  // ---------------- bottleneck (4-row weight streamers, Z=4) ----------------
  gemv8(w_btd, ws + o_E, ws + o_F, 1024, 512, 4, 0, 4);
  bnrelu(ws + o_F, ws + o_m5, 1024, 8);
  gemv8(w_btc, ws + o_F, ws + o_G, 1024, 1024, 2, 3, 4);
  bnrelu(ws + o_G, ws + o_m5, 1024, 8);

  // ---------------- decoder ----------------
  // up0: dense parity GEMM (M=512, N=64, K=27648) through k_gemm MODE 2
  {
    int K = 1024 * 27;
    float* bcol = ws + o_A;                 // 1769472 floats
    float* parts = ws + o_N;                // 64*512*64 = 2097152 floats
    k_bcolT64<<<blocks((long)K * 64), TPB, 0, stream>>>(ws + o_G, bcol, K);
    int nch = (K + 31) >> 5;                // 864
    int Z = 64;
    int kper = (nch + Z - 1) / Z;           // 14
    dim3 g(1, 512 / 64, Z);
    k_gemm<64, 2><<<g, TPB, 0, stream>>>(w_up0, bcol, nullptr, parts,
                                         512, 64, K, 4, 4, K, kper);
    k_sumscatT<<<blocks(512L * 64), TPB, 0, stream>>>(parts, ws + o_H, 512, Z);
  }
  bnrelu(ws + o_H, ws + o_m4, 512, 64);
  GEMM(64, 2, w_fu0, ws + o_H, ws + o_E, ws + o_I, 512, 64, 1024, 4, 4, 512, 32);
  bnrelu(ws + o_I, ws + o_m4, 512, 64);

  convTmerged(w_up1, ws + o_I, ws + o_J, 256, 512, 4, 2, ws + o_A, 2097152);
  bnrelu(ws + o_J, ws + o_m3, 256, 512);
  GEMM(64, 2, w_fu1, ws + o_J, ws + o_D, ws + o_K, 256, 512, 512, 8, 8, 256, 16);
  bnrelu(ws + o_K, ws + o_m3, 256, 512);

  convTmerged(w_up2, ws + o_K, ws + o_L, 128, 256, 8, 2, ws + o_A, 2097152);
  bnrelu(ws + o_L, ws + o_m2, 128, 4096);
  GEMM(64, 2, w_fu2, ws + o_L, ws + o_C, ws + o_M, 128, 4096, 256, 16, 16, 128, 2);
  bnrelu(ws + o_M, ws + o_m2, 128, 4096);

  // up3: o_N scratch (8 slices, d=32) unless tail scratch allows deeper
  convTmerged(w_up3, ws + o_M, ws + o_A, 64, 128, 16, 4, ws + o_N, 2097152);
  bnrelu(ws + o_A, ws + o_m1, 64, 32768);
  GEMM(64, 2, w_fu3, ws + o_A, ws + o_B, ws + o_N, 64, 32768, 128, 32, 32, 64, 1);
  bnrelu(ws + o_N, ws + o_m1, 64, 32768);

  // ---------------- final up: per-column kernel, weights in LDS ----------
  {
    dim3 g(32768 / TPB, 1, 8);
    k_finup<<<g, TPB, 0, stream>>>(w_fin, ws + o_N, ws + o_fin);
  }
  {
    int vox = 262144, C = 16;
    int S = 64, chunk = vox / S;
    dim3 g(S, C);
    k_stats1<<<g, TPB, 0, stream>>>(ws + o_fin, ws + o_m0, ws + o_P, ws + o_PM,
                                    vox, chunk);
    k_stats2<<<C, 64, 0, stream>>>(ws + o_P, ws + o_PM, st, S);
    long total = (long)C * vox;
    k_apply_out<<<blocks(total), TPB, 0, stream>>>(ws + o_fin, ws + o_m0, st,
                                                   out, vox, total);
  }
#undef GEMM
}

// Round 24
// 738.524 us; speedup vs baseline: 1.1023x; 1.0216x over previous
//
#include <hip/hip_runtime.h>
#include <hip/hip_bf16.h>

#define TPB 256

struct ParCfg { int zoff[9]; int kper[8]; };

// ================= masks =================
__global__ __launch_bounds__(TPB) void k_mask0(const float* __restrict__ mask,
                                               float* __restrict__ m0, int n) {
  int i = blockIdx.x * TPB + threadIdx.x;
  if (i < n) m0[i] = (mask[i] < 0.1f) ? 1.0f : 0.0f;
}

__global__ __launch_bounds__(TPB) void k_downmask(const float* __restrict__ mi,
                                                  float* __restrict__ mo, int Dout) {
  int n = Dout * Dout * Dout;
  int idx = blockIdx.x * TPB + threadIdx.x;
  if (idx >= n) return;
  int Din = Dout * 2;
  int ox = idx % Dout, oy = (idx / Dout) % Dout, oz = idx / (Dout * Dout);
  float v = 0.f;
  for (int kz = 0; kz < 3; kz++) {
    int iz = 2 * oz + kz - 1; if ((unsigned)iz >= (unsigned)Din) continue;
    for (int ky = 0; ky < 3; ky++) {
      int iy = 2 * oy + ky - 1; if ((unsigned)iy >= (unsigned)Din) continue;
      for (int kx = 0; kx < 3; kx++) {
        int ix = 2 * ox + kx - 1; if ((unsigned)ix >= (unsigned)Din) continue;
        v = fmaxf(v, mi[(iz * Din + iy) * Din + ix]);
      }
    }
  }
  mo[idx] = v;
}

__global__ __launch_bounds__(TPB) void k_maskx(const float* __restrict__ x,
                                               const float* __restrict__ m,
                                               float* __restrict__ o,
                                               long total, int vox) {
  long i = blockIdx.x * (long)TPB + threadIdx.x;
  if (i < total) o[i] = x[i] * m[i % vox];
}

__global__ __launch_bounds__(TPB) void k_sumparts(const float* __restrict__ parts,
                                                  float* __restrict__ out,
                                                  long n, int s) {
  long i = blockIdx.x * (long)TPB + threadIdx.x;
  if (i >= n) return;
  float a = 0.f;
  for (int j = 0; j < s; j++) a += parts[(long)j * n + i];
  out[i] = a;
}

// all-classes sum+scatter for the merged convT kernel
__global__ __launch_bounds__(TPB) void k_sumscatA(const float* __restrict__ parts,
                                                  float* __restrict__ out,
                                                  int lgNp, int lgMN, int Dh,
                                                  int lgDh, ParCfg pc) {
  long idx = blockIdx.x * (long)TPB + threadIdx.x;
  if (idx >= (8L << lgMN)) return;
  int cls = (int)(idx >> lgMN);
  int r = (int)(idx & ((1L << lgMN) - 1));
  int co = r >> lgNp;
  int pp = r & ((1 << lgNp) - 1);
  float s = 0.f;
  for (int z = pc.zoff[cls]; z < pc.zoff[cls + 1]; z++)
    s += parts[((long)z << lgMN) + r];
  int px = cls & 1, py = (cls >> 1) & 1, pz = (cls >> 2) & 1;
  int ox = pp & (Dh - 1), oy = (pp >> lgDh) & (Dh - 1), oz = pp >> (2 * lgDh);
  int DF = Dh * 2;
  long fc = ((long)(2 * oz + pz) * DF + (2 * oy + py)) * DF + (2 * ox + px);
  out[(long)co * ((long)DF * DF * DF) + fc] = s;
}

// ================= N=8 weight-streaming path (btd, btc) =================
__global__ __launch_bounds__(TPB) void k_bcol8(const float* __restrict__ in,
                                               float* __restrict__ Bcol,
                                               int K, int Din, int mode) {
  long idx = blockIdx.x * (long)TPB + threadIdx.x;
  if (idx >= (long)K * 8) return;
  int kg = (int)(idx >> 3), pp = (int)(idx & 7);
  int ci = kg / 27, tap = kg - ci * 27;
  int kz = tap / 9, r9 = tap - kz * 9;
  int ky = r9 / 3, kx = r9 - ky * 3;
  int oz = pp >> 2, oy = (pp >> 1) & 1, ox = pp & 1;
  int iz, iy, ix;
  if (mode == 0) { iz = 2 * oz + kz - 1; iy = 2 * oy + ky - 1; ix = 2 * ox + kx - 1; }
  else           { iz = oz + kz - 1;     iy = oy + ky - 1;     ix = ox + kx - 1; }
  float v = 0.f;
  if ((unsigned)iz < (unsigned)Din && (unsigned)iy < (unsigned)Din &&
      (unsigned)ix < (unsigned)Din)
    v = in[(long)ci * Din * Din * Din + ((long)iz * Din + iy) * Din + ix];
  Bcol[idx] = v;
}

// 4 rows per block; register double-buffer: iteration i+TPB's 12 loads are
// issued BEFORE iteration i's FMAs, so the FMA waitcnt leaves them in flight
// (hides HBM latency). Per-thread FMA order identical to the serial version.
__global__ __launch_bounds__(TPB) void k_gemv8d(const float* __restrict__ W,
                                                const float* __restrict__ Bcol,
                                                float* __restrict__ part,
                                                int M, int K, int kqPer) {
  const int t = threadIdx.x;
  const int co0 = blockIdx.x * 4;
  const int kq = K >> 2;
  int q0 = blockIdx.y * kqPer;
  int q1 = q0 + kqPer; if (q1 > kq) q1 = kq;
  float acc[4][8];
#pragma unroll
  for (int r = 0; r < 4; r++)
#pragma unroll
    for (int p = 0; p < 8; p++) acc[r][p] = 0.f;
  const float4* W4 = (const float4*)W;

  float4 wc[4], wn[4], bcv[8], bnv[8];
  auto loadW = [&](int i, float4 (&w)[4]) {
#pragma unroll
    for (int r = 0; r < 4; r++) w[r] = W4[(long)(co0 + r) * kq + i];
  };
  auto loadBv = [&](int i, float4 (&b)[8]) {
    const float4* bp = (const float4*)&Bcol[(long)i * 32];
#pragma unroll
    for (int j = 0; j < 8; j++) b[j] = bp[j];
  };

  int i = q0 + t;
  if (i < q1) { loadW(i, wc); loadBv(i, bcv); }
  while (i < q1) {
    const int inx = i + TPB;
    if (inx < q1) { loadW(inx, wn); loadBv(inx, bnv); }   // prefetch
#pragma unroll
    for (int j = 0; j < 4; j++) {
      const float4 b0 = bcv[j * 2];
      const float4 b1 = bcv[j * 2 + 1];
#pragma unroll
      for (int r = 0; r < 4; r++) {
        const float w = (j == 0) ? wc[r].x : (j == 1) ? wc[r].y
                        : (j == 2) ? wc[r].z : wc[r].w;
        acc[r][0] += w * b0.x; acc[r][1] += w * b0.y;
        acc[r][2] += w * b0.z; acc[r][3] += w * b0.w;
        acc[r][4] += w * b1.x; acc[r][5] += w * b1.y;
        acc[r][6] += w * b1.z; acc[r][7] += w * b1.w;
      }
    }
    i = inx;
    if (i < q1) {
#pragma unroll
      for (int r = 0; r < 4; r++) wc[r] = wn[r];
#pragma unroll
      for (int j = 0; j < 8; j++) bcv[j] = bnv[j];
    }
  }
#pragma unroll
  for (int off = 32; off > 0; off >>= 1)
#pragma unroll
    for (int r = 0; r < 4; r++)
#pragma unroll
      for (int p = 0; p < 8; p++) acc[r][p] += __shfl_down(acc[r][p], off);
  __shared__ float Rs[4][4][8];
  if ((t & 63) == 0) {
#pragma unroll
    for (int r = 0; r < 4; r++)
#pragma unroll
      for (int p = 0; p < 8; p++) Rs[t >> 6][r][p] = acc[r][p];
  }
  __syncthreads();
  if (t < 32) {
    int r = t >> 3, p = t & 7;
    part[((long)blockIdx.y * M + co0 + r) * 8 + p] =
        Rs[0][r][p] + Rs[1][r][p] + Rs[2][r][p] + Rs[3][r][p];
  }
}

// ============ up0: dense parity im2colT, Bcol64[K][64] ============
__global__ __launch_bounds__(TPB) void k_bcolT64(const float* __restrict__ in,
                                                 float* __restrict__ B, int K) {
  long idx = blockIdx.x * (long)TPB + threadIdx.x;
  if (idx >= (long)K * 64) return;
  int kg = (int)(idx >> 6), q = (int)(idx & 63);
  int ci = kg / 27, tap = kg - ci * 27;
  int kz = tap / 9, r9 = tap - kz * 9;
  int ky = r9 / 3, kx = r9 - ky * 3;
  int clsT = ((kz & 1) << 2) | ((ky & 1) << 1) | (kx & 1);
  int cls = q >> 3, p = q & 7;
  float v = 0.f;
  if (cls == clsT) {
    int oxh = p & 1, oyh = (p >> 1) & 1, ozh = p >> 2;
    int cx = (kx + (kx & 1)) >> 1;
    int cy = (ky + (ky & 1)) >> 1;
    int cz = (kz + (kz & 1)) >> 1;
    int ix = oxh + cx - 1, iy = oyh + cy - 1, iz = ozh + cz - 1;
    if ((unsigned)ix < 2u && (unsigned)iy < 2u && (unsigned)iz < 2u)
      v = in[(long)ci * 8 + (iz * 2 + iy) * 2 + ix];
  }
  B[idx] = v;
}

// sum split-K partials and scatter [cls][p] -> strided 4^3 grid
__global__ __launch_bounds__(TPB) void k_sumscatT(const float* __restrict__ parts,
                                                  float* __restrict__ out,
                                                  int M, int Z) {
  long idx = blockIdx.x * (long)TPB + threadIdx.x;
  if (idx >= (long)M * 64) return;
  int row = (int)(idx >> 6), q = (int)(idx & 63);
  float s = 0.f;
  for (int z = 0; z < Z; z++) s += parts[((long)z * M + row) * 64 + q];
  int cls = q >> 3, p = q & 7;
  int px = cls & 1, py = (cls >> 1) & 1, pz = (cls >> 2) & 1;
  int oxh = p & 1, oyh = (p >> 1) & 1, ozh = p >> 2;
  int fc = (2 * ozh + pz) * 16 + (2 * oyh + py) * 4 + (2 * oxh + px);
  out[(long)row * 64 + fc] = s;
}

// ================= tiled implicit-GEMM, split-K, reg-prefetch =================
// MODE 0: conv k3 s2 p1   MODE 2: 1x1 concat-fuse / dense B   MODE 3: conv k3 s1 p1
template<int MT, int MODE>
__global__ __launch_bounds__(TPB) void k_gemm(const float* __restrict__ A,
                                              const float* __restrict__ B1,
                                              const float* __restrict__ B2,
                                              float* __restrict__ C,
                                              int M, int N, int K,
                                              int Din, int Dout, int C1,
                                              int kcPer) {
  constexpr int MR = MT / 16;
  constexpr int AEL = (MT == 64) ? 8 : 2;
  __shared__ __align__(16) float At[32][MT];
  __shared__ __align__(16) float Bt[32][64];

  const int t = threadIdx.x;
  const int n0 = blockIdx.x * 64;
  const int m0 = blockIdx.y * MT;

  const int p0 = (t & 15) * 4;
  const int co0 = (t >> 4) * MR;

  const int pb = t & 63;
  const int kb0 = (t >> 6) * 8;
  const int pp = n0 + pb;
  const int oxb = pp & (Dout - 1);
  const int oyb = (pp / Dout) & (Dout - 1);
  const int ozb = pp / (Dout * Dout);

  const int nch = (K + 31) >> 5;
  const int c0 = blockIdx.z * kcPer;
  int c1 = c0 + kcPer; if (c1 > nch) c1 = nch;

  float acc[MR][4];
#pragma unroll
  for (int a = 0; a < MR; a++)
#pragma unroll
    for (int b = 0; b < 4; b++) acc[a][b] = 0.f;

  float raf[AEL];
  float rb[8];
  const int co_a = (MT == 64) ? (t >> 2) : (t & 15);
  const int ka   = (MT == 64) ? ((t & 3) * 8) : ((t >> 4) * 2);
  const long arow = (long)(m0 + co_a) * K;

  auto loadA = [&](int c) {
    const int k0 = c << 5;
    if (MT == 64) {
#pragma unroll
      for (int j = 0; j < 2; j++) {
        const int kg = k0 + ka + j * 4;
        float4 v = (kg < K) ? *(const float4*)&A[arow + kg]
                            : make_float4(0.f, 0.f, 0.f, 0.f);
        raf[j * 4 + 0] = v.x; raf[j * 4 + 1] = v.y;
        raf[j * 4 + 2] = v.z; raf[j * 4 + 3] = v.w;
      }
    } else {
      const int kg = k0 + ka;
      raf[0] = (kg < K) ? A[arow + kg] : 0.f;
      raf[1] = (kg + 1 < K) ? A[arow + kg + 1] : 0.f;
    }
  };

  auto loadB = [&](int c) {
    const int k0 = c << 5;
#pragma unroll
    for (int j = 0; j < 8; j++) {
      const int kg = k0 + kb0 + j;
      float v = 0.f;
      if (kg < K && pp < N) {
        if (MODE == 2) {
          v = (kg < C1) ? B1[(long)kg * N + pp] : B2[(long)(kg - C1) * N + pp];
        } else {
          const int ci = kg / 27;
          const int tap = kg - ci * 27;
          const int kz = tap / 9;
          const int r9 = tap - kz * 9;
          const int ky = r9 / 3;
          const int kx = r9 - ky * 3;
          int iz, iy, ix;
          bool ok;
          if (MODE == 0) {
            iz = 2 * ozb + kz - 1; iy = 2 * oyb + ky - 1; ix = 2 * oxb + kx - 1;
            ok = (unsigned)iz < (unsigned)Din && (unsigned)iy < (unsigned)Din &&
                 (unsigned)ix < (unsigned)Din;
          } else { // MODE 3
            iz = ozb + kz - 1; iy = oyb + ky - 1; ix = oxb + kx - 1;
            ok = (unsigned)iz < (unsigned)Din && (unsigned)iy < (unsigned)Din &&
                 (unsigned)ix < (unsigned)Din;
          }
          if (ok)
            v = B1[(long)ci * Din * Din * Din + ((long)iz * Din + iy) * Din + ix];
        }
      }
      rb[j] = v;
    }
  };

  if (c0 < c1) { loadA(c0); loadB(c0); }

  for (int c = c0; c < c1; ++c) {
    __syncthreads();
#pragma unroll
    for (int j = 0; j < AEL; j++) At[ka + j][co_a] = raf[j];
#pragma unroll
    for (int j = 0; j < 8; j++) Bt[kb0 + j][pb] = rb[j];
    if (c + 1 < c1) { loadA(c + 1); loadB(c + 1); }
    __syncthreads();
#pragma unroll
    for (int kk = 0; kk < 32; ++kk) {
      const float4 b4 = *(const float4*)&Bt[kk][p0];
      if (MR == 4) {
        const float4 a4 = *(const float4*)&At[kk][co0];
        acc[0][0] += a4.x * b4.x; acc[0][1] += a4.x * b4.y;
        acc[0][2] += a4.x * b4.z; acc[0][3] += a4.x * b4.w;
        acc[1][0] += a4.y * b4.x; acc[1][1] += a4.y * b4.y;
        acc[1][2] += a4.y * b4.z; acc[1][3] += a4.y * b4.w;
        acc[2][0] += a4.z * b4.x; acc[2][1] += a4.z * b4.y;
        acc[2][2] += a4.z * b4.z; acc[2][3] += a4.z * b4.w;
        acc[3][0] += a4.w * b4.x; acc[3][1] += a4.w * b4.y;
        acc[3][2] += a4.w * b4.z; acc[3][3] += a4.w * b4.w;
      } else {
        const float a = At[kk][co0];
        acc[0][0] += a * b4.x; acc[0][1] += a * b4.y;
        acc[0][2] += a * b4.z; acc[0][3] += a * b4.w;
      }
    }
  }

  float* Cz = C + (long)blockIdx.z * ((long)M * N);
#pragma unroll
  for (int mr = 0; mr < MR; mr++) {
    if (n0 + p0 < N) {
      float4 v = make_float4(acc[mr][0], acc[mr][1], acc[mr][2], acc[mr][3]);
      *(float4*)&Cz[(long)(m0 + co0 + mr) * N + n0 + p0] = v;
    }
  }
}

// ================= merged convT-parity GEMM (up1..up3), 3D grid ============
__global__ __launch_bounds__(TPB) void k_gemmTm(const float* __restrict__ A,
                                                const float* __restrict__ B1,
                                                float* __restrict__ C,
                                                int M, int N, int Cin, int Din,
                                                ParCfg pc) {
  __shared__ __align__(16) float At[32][64];
  __shared__ __align__(16) float Bt[32][64];

  const int t = threadIdx.x;
  const int n0 = blockIdx.x * 64;
  const int m0 = blockIdx.y * 64;
  const int z = blockIdx.z;

  int cls = 0;
#pragma unroll
  for (int c = 1; c < 8; c++) if (z >= pc.zoff[c]) cls = c;
  const int zi = z - pc.zoff[cls];
  const int kperc = pc.kper[cls];

  const int px = cls & 1, py = (cls >> 1) & 1, pz = (cls >> 2) & 1;
  const int lgnx = 1 - px, lgny = 1 - py;
  const int lgT = lgnx + lgny + (1 - pz);
  const int T = 1 << lgT;
  const int K = Cin << lgT;
  const int nch = K >> 5;

  const int p0 = (t & 15) * 4;
  const int co0 = (t >> 4) * 4;
  const int pb = t & 63;
  const int kb0 = (t >> 6) * 8;      // wave-uniform
  const int pp = n0 + pb;
  const int oxb = pp & (Din - 1);
  const int oyb = (pp / Din) & (Din - 1);
  const int ozb = pp / (Din * Din);
  const long vin = (long)Din * Din * Din;

  const int bz = ozb - 1 + pz, by = oyb - 1 + py, bx = oxb - 1 + px;
  const long laneOff = (long)bz * Din * Din + (long)by * Din + bx;
  unsigned vmask = 0;
  if (pp < N) {
    int nz_ = pz ? 1 : 2, ny_ = py ? 1 : 2, nx_ = px ? 1 : 2;
    for (int tz = 0; tz < nz_; tz++)
      for (int ty = 0; ty < ny_; ty++)
        for (int tx = 0; tx < nx_; tx++) {
          bool ok = (unsigned)(bz + tz) < (unsigned)Din &&
                    (unsigned)(by + ty) < (unsigned)Din &&
                    (unsigned)(bx + tx) < (unsigned)Din;
          if (ok) vmask |= 1u << ((tz << (lgny + lgnx)) | (ty << lgnx) | tx);
        }
  }

  const int c0 = zi * kperc;
  int c1 = c0 + kperc; if (c1 > nch) c1 = nch;

  float acc[4][4];
#pragma unroll
  for (int a = 0; a < 4; a++)
#pragma unroll
    for (int b = 0; b < 4; b++) acc[a][b] = 0.f;

  float raf[8];
  float rb[8];
  const int co_a = t & 63;
  const int ka   = (t >> 6) * 8;
  const long abase = (long)(m0 + co_a) * Cin * 27;

  auto loadA = [&](int c) {
    const int k0 = c << 5;
#pragma unroll
    for (int j = 0; j < 8; j++) {
      const int kg = k0 + ka + j;
      float v = 0.f;
      if (kg < K) {
        int ci = kg >> lgT;
        int tt = kg & (T - 1);
        int tx = tt & ((1 << lgnx) - 1);
        int r = tt >> lgnx;
        int ty = r & ((1 << lgny) - 1);
        int tz = r >> lgny;
        int kx = px ? 1 : (tx << 1);
        int ky = py ? 1 : (ty << 1);
        int kz = pz ? 1 : (tz << 1);
        v = A[abase + ci * 27 + (kz * 3 + ky) * 3 + kx];
      }
      raf[j] = v;
    }
  };

  auto loadB = [&](int c) {
    const int k0 = c << 5;
#pragma unroll
    for (int j = 0; j < 8; j++) {
      const int kg = k0 + kb0 + j;
      float v = 0.f;
      if (kg < K) {
        int ci = kg >> lgT;
        int tt = kg & (T - 1);
        int tx = tt & ((1 << lgnx) - 1);
        int r = tt >> lgnx;
        int ty = r & ((1 << lgny) - 1);
        int tz = r >> lgny;
        long base = (long)ci * vin + (long)tz * Din * Din + ty * Din + tx;
        if ((vmask >> tt) & 1) v = B1[base + laneOff];
      }
      rb[j] = v;
    }
  };

  if (c0 < c1) { loadA(c0); loadB(c0); }

  for (int c = c0; c < c1; ++c) {
    __syncthreads();
#pragma unroll
    for (int j = 0; j < 8; j++) At[ka + j][co_a] = raf[j];
#pragma unroll
    for (int j = 0; j < 8; j++) Bt[kb0 + j][pb] = rb[j];
    if (c + 1 < c1) { loadA(c + 1); loadB(c + 1); }
    __syncthreads();
#pragma unroll
    for (int kk = 0; kk < 32; ++kk) {
      const float4 b4 = *(const float4*)&Bt[kk][p0];
      const float4 a4 = *(const float4*)&At[kk][co0];
      acc[0][0] += a4.x * b4.x; acc[0][1] += a4.x * b4.y;
      acc[0][2] += a4.x * b4.z; acc[0][3] += a4.x * b4.w;
      acc[1][0] += a4.y * b4.x; acc[1][1] += a4.y * b4.y;
      acc[1][2] += a4.y * b4.z; acc[1][3] += a4.y * b4.w;
      acc[2][0] += a4.z * b4.x; acc[2][1] += a4.z * b4.y;
      acc[2][2] += a4.z * b4.z; acc[2][3] += a4.z * b4.w;
      acc[3][0] += a4.w * b4.x; acc[3][1] += a4.w * b4.y;
      acc[3][2] += a4.w * b4.z; acc[3][3] += a4.w * b4.w;
    }
  }

  float* Cz = C + (long)z * ((long)M * N);
#pragma unroll
  for (int mr = 0; mr < 4; mr++) {
    if (n0 + p0 < N) {
      float4 v = make_float4(acc[mr][0], acc[mr][1], acc[mr][2], acc[mr][3]);
      *(float4*)&Cz[(long)(m0 + co0 + mr) * N + n0 + p0] = v;
    }
  }
}

// ================= final-up: M=16, per-column kernel, reg-prefetch ==========
__global__ __launch_bounds__(TPB) void k_finup(const float* __restrict__ A,
                                               const float* __restrict__ B1,
                                               float* __restrict__ C) {
  __shared__ __align__(16) float Ws[8192];
  const int cls = blockIdx.z;
  const int px = cls & 1, py = (cls >> 1) & 1, pz = (cls >> 2) & 1;
  const int lgnx = 1 - px, lgny = 1 - py;
  const int lgT = lgnx + lgny + (1 - pz);
  const int T = 1 << lgT;
  const int K = 64 << lgT;

  for (int idx = threadIdx.x; idx < K * 16; idx += TPB) {
    int k = idx >> 4, co = idx & 15;
    int ci = k >> lgT;
    int tt = k & (T - 1);
    int tx = tt & ((1 << lgnx) - 1);
    int r = tt >> lgnx;
    int ty = r & ((1 << lgny) - 1);
    int tz = r >> lgny;
    int kx = px ? 1 : (tx << 1);
    int ky = py ? 1 : (ty << 1);
    int kz = pz ? 1 : (tz << 1);
    Ws[idx] = A[((long)co * 64 + ci) * 27 + (kz * 3 + ky) * 3 + kx];
  }

  const int pp = blockIdx.x * TPB + threadIdx.x;
  const int oxb = pp & 31, oyb = (pp >> 5) & 31, ozb = pp >> 10;
  const int bz = ozb - 1 + pz, by = oyb - 1 + py, bx = oxb - 1 + px;
  const long laneOff = (long)bz * 1024 + by * 32 + bx;
  unsigned vmask = 0;
  {
    int nz_ = pz ? 1 : 2, ny_ = py ? 1 : 2, nx_ = px ? 1 : 2;
    for (int tz = 0; tz < nz_; tz++)
      for (int ty = 0; ty < ny_; ty++)
        for (int tx = 0; tx < nx_; tx++) {
          bool ok = (unsigned)(bz + tz) < 32u && (unsigned)(by + ty) < 32u &&
                    (unsigned)(bx + tx) < 32u;
          if (ok) vmask |= 1u << ((tz << (lgny + lgnx)) | (ty << lgnx) | tx);
        }
  }

  int toff[8];
#pragma unroll
  for (int tt = 0; tt < 8; tt++) {
    int tx = tt & ((1 << lgnx) - 1);
    int r = tt >> lgnx;
    int ty = r & ((1 << lgny) - 1);
    int tz = r >> lgny;
    toff[tt] = tz * 1024 + ty * 32 + tx;
  }
  __syncthreads();

  float acc[16];
#pragma unroll
  for (int co = 0; co < 16; co++) acc[co] = 0.f;

  float bcur[8], bnxt[8];
  auto loadG = [&](int ci, float (&bv)[8]) {
#pragma unroll
    for (int tt = 0; tt < 8; tt++) {
      if (tt < T)
        bv[tt] = ((vmask >> tt) & 1)
                     ? B1[(long)ci * 32768 + toff[tt] + laneOff] : 0.f;
      else
        bv[tt] = 0.f;
    }
  };

  loadG(0, bcur);
  for (int ci = 0; ci < 64; ci++) {
    if (ci + 1 < 64) loadG(ci + 1, bnxt);
#pragma unroll
    for (int tt = 0; tt < 8; tt++) {
      if (tt < T) {
        const float b = bcur[tt];
        const float4* wp = (const float4*)&Ws[((ci << lgT) + tt) * 16];
#pragma unroll
        for (int q = 0; q < 4; q++) {
          float4 w = wp[q];
          acc[q * 4 + 0] += w.x * b;
          acc[q * 4 + 1] += w.y * b;
          acc[q * 4 + 2] += w.z * b;
          acc[q * 4 + 3] += w.w * b;
        }
      }
    }
#pragma unroll
    for (int tt = 0; tt < 8; tt++) bcur[tt] = bnxt[tt];
  }

  const long fc = ((long)(2 * ozb + pz) * 64 + (2 * oyb + py)) * 64 +
                  (2 * oxb + px);
#pragma unroll
  for (int co = 0; co < 16; co++) C[(long)co * 262144 + fc] = acc[co];
}

// ================= hierarchical masked BN stats =================
__global__ __launch_bounds__(TPB) void k_stats1(const float* __restrict__ a,
                                                const float* __restrict__ m,
                                                float* __restrict__ part,
                                                float* __restrict__ partM,
                                                int vox, int chunk) {
  const int s = blockIdx.x, c = blockIdx.y;
  const float* ap = a + (long)c * vox + (long)s * chunk;
  const float* mp = m + (long)s * chunk;
  float s0 = 0.f, s1 = 0.f, sm = 0.f;
  for (int i = threadIdx.x; i < chunk; i += TPB) {
    float mv = mp[i];
    float v = ap[i] * mv;
    s0 += v; s1 += v * v; sm += mv;
  }
  __shared__ float sh0[TPB], sh1[TPB], sh2[TPB];
  sh0[threadIdx.x] = s0; sh1[threadIdx.x] = s1; sh2[threadIdx.x] = sm;
  __syncthreads();
  for (int off = TPB / 2; off > 0; off >>= 1) {
    if (threadIdx.x < off) {
      sh0[threadIdx.x] += sh0[threadIdx.x + off];
      sh1[threadIdx.x] += sh1[threadIdx.x + off];
      sh2[threadIdx.x] += sh2[threadIdx.x + off];
    }
    __syncthreads();
  }
  if (threadIdx.x == 0) {
    const int S = gridDim.x;
    part[(c * S + s) * 2] = sh0[0];
    part[(c * S + s) * 2 + 1] = sh1[0];
    if (c == 0) partM[s] = sh2[0];
  }
}

__global__ __launch_bounds__(64) void k_stats2(const float* __restrict__ part,
                                               const float* __restrict__ partM,
                                               float* __restrict__ stats, int S) {
  const int c = blockIdx.x, t = threadIdx.x;
  float s0 = 0.f, s1 = 0.f, sm = 0.f;
  for (int s = t; s < S; s += 64) {
    s0 += part[(c * S + s) * 2];
    s1 += part[(c * S + s) * 2 + 1];
    sm += partM[s];
  }
  for (int off = 32; off > 0; off >>= 1) {
    s0 += __shfl_down(s0, off);
    s1 += __shfl_down(s1, off);
    sm += __shfl_down(sm, off);
  }
  if (t == 0) {
    float n = fmaxf(sm, 1.f);
    float mu = s0 / n;
    float var = fmaxf(s1 / n - mu * mu, 0.f);
    stats[2 * c] = mu;
    stats[2 * c + 1] = rsqrtf(var + 1e-5f);
  }
}

__global__ __launch_bounds__(TPB) void k_apply(float* __restrict__ a,
                                               const float* __restrict__ m,
                                               const float* __restrict__ stats,
                                               int vox, long total) {
  long idx = blockIdx.x * (long)TPB + threadIdx.x;
  if (idx >= total) return;
  int c = (int)(idx / vox);
  int p = (int)(idx % vox);
  float v = (a[idx] - stats[2 * c]) * stats[2 * c + 1];
  a[idx] = fmaxf(v, 0.f) * m[p];
}

__global__ __launch_bounds__(TPB) void k_apply_out(const float* __restrict__ a,
                                                   const float* __restrict__ m,
                                                   const float* __restrict__ stats,
                                                   float* __restrict__ out,
                                                   int vox, long total) {
  long idx = blockIdx.x * (long)TPB + threadIdx.x;
  if (idx >= total) return;
  int c = (int)(idx / vox);
  int p = (int)(idx % vox);
  float v = (a[idx] - stats[2 * c]) * stats[2 * c + 1];
  out[idx] = fmaxf(v, 0.f) * m[p];
}

// ================= workspace layout (floats) =================
constexpr long o_m0 = 0;
constexpr long o_m1 = 262144;
constexpr long o_m2 = 294912;
constexpr long o_m3 = 299008;
constexpr long o_m4 = 299520;
constexpr long o_m5 = 299584;
constexpr long o_st = 299592;
constexpr long o_A  = 301696;     // 2M: xm -> scratch -> u3 -> fin
constexpr long o_B  = 2398848;    // 2M: a0
constexpr long o_C  = 4496000;    // 512K: a1
constexpr long o_D  = 5020288;    // 128K: a2
constexpr long o_E  = 5151360;    // 32K: a3
constexpr long o_F  = 5184128;    // 8K: a4
constexpr long o_G  = 5192320;    // 8K: a5
constexpr long o_H  = 5200512;    // 32K: u0
constexpr long o_I  = 5233280;    // 32K: f0
constexpr long o_J  = 5266048;    // 128K: u1
constexpr long o_K  = 5397120;    // 128K: f1
constexpr long o_L  = 5528192;    // 512K: u2
constexpr long o_M  = 6052480;    // 512K: f2
constexpr long o_N  = 6576768;    // 2M: f3 (up0/up3 scratch before fu3)
constexpr long o_P  = 8673920;    // BN partials
constexpr long o_PM = 8690304;
constexpr long o_S  = 8690368;    // tail scratch (size = ws_size/4 - o_S)
constexpr long o_fin = o_A;

extern "C" void kernel_launch(void* const* d_in, const int* in_sizes, int n_in,
                              void* d_out, int out_size, void* d_ws, size_t ws_size,
                              hipStream_t stream) {
  const float* x      = (const float*)d_in[0];
  const float* mask   = (const float*)d_in[1];
  const float* w_enc0 = (const float*)d_in[2];
  const float* w_enc1 = (const float*)d_in[3];
  const float* w_enc2 = (const float*)d_in[4];
  const float* w_enc3 = (const float*)d_in[5];
  const float* w_btd  = (const float*)d_in[6];
  const float* w_btc  = (const float*)d_in[7];
  const float* w_up0  = (const float*)d_in[8];
  const float* w_fu0  = (const float*)d_in[9];
  const float* w_up1  = (const float*)d_in[10];
  const float* w_fu1  = (const float*)d_in[11];
  const float* w_up2  = (const float*)d_in[12];
  const float* w_fu2  = (const float*)d_in[13];
  const float* w_up3  = (const float*)d_in[14];
  const float* w_fu3  = (const float*)d_in[15];
  const float* w_fin  = (const float*)d_in[16];

  float* ws = (float*)d_ws;
  float* st = ws + o_st;
  float* out = (float*)d_out;

  long tailCap = (long)(ws_size / 4) - o_S;
  if (tailCap < 0) tailCap = 0;

  auto blocks = [](long n) { return (unsigned)((n + TPB - 1) / TPB); };

  // masks
  k_mask0<<<blocks(262144), TPB, 0, stream>>>(mask, ws + o_m0, 262144);
  k_downmask<<<blocks(32768), TPB, 0, stream>>>(ws + o_m0, ws + o_m1, 32);
  k_downmask<<<blocks(4096), TPB, 0, stream>>>(ws + o_m1, ws + o_m2, 16);
  k_downmask<<<blocks(512), TPB, 0, stream>>>(ws + o_m2, ws + o_m3, 8);
  k_downmask<<<blocks(64), TPB, 0, stream>>>(ws + o_m3, ws + o_m4, 4);
  k_downmask<<<blocks(8), TPB, 0, stream>>>(ws + o_m4, ws + o_m5, 2);

  // masked input -> A
  k_maskx<<<blocks(8L * 262144), TPB, 0, stream>>>(x, ws + o_m0, ws + o_A,
                                                   8L * 262144, 262144);

  auto stats = [&](const float* a, const float* m, int C, int vox) {
    int S = vox / TPB; if (S < 1) S = 1; if (S > 64) S = 64;
    int chunk = vox / S;
    dim3 g(S, C);
    k_stats1<<<g, TPB, 0, stream>>>(a, m, ws + o_P, ws + o_PM, vox, chunk);
    k_stats2<<<C, 64, 0, stream>>>(ws + o_P, ws + o_PM, st, S);
  };
  auto bnrelu = [&](float* a, const float* m, int C, int vox) {
    stats(a, m, C, vox);
    long total = (long)C * vox;
    k_apply<<<blocks(total), TPB, 0, stream>>>(a, m, st, vox, total);
  };

#define GEMM(MT, MODE, A_, B1_, B2_, O_, M_, N_, K_, DIN_, DOUT_, C1_, Z_)   \
  do {                                                                        \
    int nch_ = ((K_) + 31) >> 5;                                              \
    int kper_ = (nch_ + (Z_) - 1) / (Z_);                                     \
    dim3 g_(((N_) + 63) / 64, (M_) / (MT), (Z_));                             \
    float* dst_ = ((Z_) > 1) ? (ws + o_A) : (O_);                             \
    k_gemm<MT, MODE><<<g_, TPB, 0, stream>>>(A_, B1_, B2_, dst_, M_, N_, K_,  \
                                             DIN_, DOUT_, C1_, kper_);        \
    if ((Z_) > 1)                                                             \
      k_sumparts<<<blocks((long)(M_) * (N_)), TPB, 0, stream>>>(              \
          ws + o_A, O_, (long)(M_) * (N_), (Z_));                             \
  } while (0)

  // merged convT: adaptive split-K depth (3D grid)
  auto convTmerged = [&](const float* w, const float* in, float* o, int M,
                         int Cin, int Dh, int dMin, float* scrP, long scrPcap) {
    int lgDh = 31 - __builtin_clz(Dh);
    int Np = Dh * Dh * Dh;
    long unit = (long)M * Np;
    float* scr = scrP;
    long cap = scrPcap;
    if (tailCap > cap) { scr = ws + o_S; cap = tailCap; }
    int d = dMin, slices = 0;
    for (;;) {
      slices = 0;
      for (int c = 0; c < 8; c++) {
        int px = c & 1, py = (c >> 1) & 1, pz = (c >> 2) & 1;
        int T = 1 << ((1 - px) + (1 - py) + (1 - pz));
        int nch = (Cin * T) >> 5;
        slices += (nch + d - 1) / d;
      }
      if ((long)slices * unit <= cap || d >= 256) break;
      d <<= 1;
    }
    ParCfg pc;
    int acc = 0;
    for (int c = 0; c < 8; c++) {
      pc.zoff[c] = acc;
      int px = c & 1, py = (c >> 1) & 1, pz = (c >> 2) & 1;
      int T = 1 << ((1 - px) + (1 - py) + (1 - pz));
      int nch = (Cin * T) >> 5;
      pc.kper[c] = d;
      acc += (nch + d - 1) / d;
    }
    pc.zoff[8] = acc;
    dim3 g((Np + 63) / 64, M / 64, acc);
    k_gemmTm<<<g, TPB, 0, stream>>>(w, in, scr, M, Np, Cin, Dh, pc);
    int lgNp = 3 * lgDh;
    int lgMN = lgNp + (31 - __builtin_clz(M));
    k_sumscatA<<<blocks(8L << lgMN), TPB, 0, stream>>>(scr, o, lgNp, lgMN,
                                                       Dh, lgDh, pc);
  };

  // N=8 weight-streaming GEMV, 4 rows/block (btd, btc), Z=4, reg double-buffer
  auto gemv8 = [&](const float* w, const float* in, float* o, int M, int Cin,
                   int Din, int mode, int Z) {
    int K = Cin * 27;
    float* bcol = ws + o_A;
    float* parts = ws + o_A + 262144;
    k_bcol8<<<blocks((long)K * 8), TPB, 0, stream>>>(in, bcol, K, Din, mode);
    int kq = K >> 2;
    int kqPer = (kq + Z - 1) / Z;
    dim3 g(M / 4, Z);
    k_gemv8d<<<g, TPB, 0, stream>>>(w, bcol, parts, M, K, kqPer);
    k_sumparts<<<blocks((long)M * 8), TPB, 0, stream>>>(parts, o, (long)M * 8, Z);
  };

  // ---------------- encoder ----------------
  GEMM(64, 0, w_enc0, ws + o_A, nullptr, ws + o_B, 64, 32768, 8 * 27, 64, 32, 0, 1);
  bnrelu(ws + o_B, ws + o_m1, 64, 32768);
  GEMM(64, 0, w_enc1, ws + o_B, nullptr, ws + o_C, 128, 4096, 64 * 27, 32, 16, 0, 4);
  bnrelu(ws + o_C, ws + o_m2, 128, 4096);
  GEMM(64, 0, w_enc2, ws + o_C, nullptr, ws + o_D, 256, 512, 128 * 27, 16, 8, 0, 16);
  bnrelu(ws + o_D, ws + o_m3, 256, 512);
  GEMM(64, 0, w_enc3, ws + o_D, nullptr, ws + o_E, 512, 64, 256 * 27, 8, 4, 0, 64);
  bnrelu(ws + o_E, ws + o_m4, 512, 64);

  // ---------------- bottleneck (4-row weight streamers, Z=4) ----------------
  gemv8(w_btd, ws + o_E, ws + o_F, 1024, 512, 4, 0, 4);
  bnrelu(ws + o_F, ws + o_m5, 1024, 8);
  gemv8(w_btc, ws + o_F, ws + o_G, 1024, 1024, 2, 3, 4);
  bnrelu(ws + o_G, ws + o_m5, 1024, 8);

  // ---------------- decoder ----------------
  // up0: dense parity GEMM (M=512, N=64, K=27648) through k_gemm MODE 2
  {
    int K = 1024 * 27;
    float* bcol = ws + o_A;                 // 1769472 floats
    float* parts = ws + o_N;                // 64*512*64 = 2097152 floats
    k_bcolT64<<<blocks((long)K * 64), TPB, 0, stream>>>(ws + o_G, bcol, K);
    int nch = (K + 31) >> 5;                // 864
    int Z = 64;
    int kper = (nch + Z - 1) / Z;           // 14
    dim3 g(1, 512 / 64, Z);
    k_gemm<64, 2><<<g, TPB, 0, stream>>>(w_up0, bcol, nullptr, parts,
                                         512, 64, K, 4, 4, K, kper);
    k_sumscatT<<<blocks(512L * 64), TPB, 0, stream>>>(parts, ws + o_H, 512, Z);
  }
  bnrelu(ws + o_H, ws + o_m4, 512, 64);
  GEMM(64, 2, w_fu0, ws + o_H, ws + o_E, ws + o_I, 512, 64, 1024, 4, 4, 512, 32);
  bnrelu(ws + o_I, ws + o_m4, 512, 64);

  convTmerged(w_up1, ws + o_I, ws + o_J, 256, 512, 4, 2, ws + o_A, 2097152);
  bnrelu(ws + o_J, ws + o_m3, 256, 512);
  GEMM(64, 2, w_fu1, ws + o_J, ws + o_D, ws + o_K, 256, 512, 512, 8, 8, 256, 16);
  bnrelu(ws + o_K, ws + o_m3, 256, 512);

  convTmerged(w_up2, ws + o_K, ws + o_L, 128, 256, 8, 2, ws + o_A, 2097152);
  bnrelu(ws + o_L, ws + o_m2, 128, 4096);
  GEMM(64, 2, w_fu2, ws + o_L, ws + o_C, ws + o_M, 128, 4096, 256, 16, 16, 128, 2);
  bnrelu(ws + o_M, ws + o_m2, 128, 4096);

  // up3: o_N scratch (8 slices, d=32) unless tail scratch allows deeper
  convTmerged(w_up3, ws + o_M, ws + o_A, 64, 128, 16, 4, ws + o_N, 2097152);
  bnrelu(ws + o_A, ws + o_m1, 64, 32768);
  GEMM(64, 2, w_fu3, ws + o_A, ws + o_B, ws + o_N, 64, 32768, 128, 32, 32, 64, 1);
  bnrelu(ws + o_N, ws + o_m1, 64, 32768);

  // ---------------- final up: per-column kernel, weights in LDS ----------
  {
    dim3 g(32768 / TPB, 1, 8);
    k_finup<<<g, TPB, 0, stream>>>(w_fin, ws + o_N, ws + o_fin);
  }
  {
    int vox = 262144, C = 16;
    int S = 64, chunk = vox / S;
    dim3 g(S, C);
    k_stats1<<<g, TPB, 0, stream>>>(ws + o_fin, ws + o_m0, ws + o_P, ws + o_PM,
                                    vox, chunk);
    k_stats2<<<C, 64, 0, stream>>>(ws + o_P, ws + o_PM, st, S);
    long total = (long)C * vox;
    k_apply_out<<<blocks(total), TPB, 0, stream>>>(ws + o_fin, ws + o_m0, st,
                                                   out, vox, total);
  }
#undef GEMM
}

// Round 25
// 737.210 us; speedup vs baseline: 1.1042x; 1.0018x over previous
//
#include <hip/hip_runtime.h>
#include <hip/hip_bf16.h>

#define TPB 256

struct ParCfg { int zoff[9]; int kper[8]; };

// ================= masks =================
__global__ __launch_bounds__(TPB) void k_mask0(const float* __restrict__ mask,
                                               float* __restrict__ m0, int n) {
  int i = blockIdx.x * TPB + threadIdx.x;
  if (i < n) m0[i] = (mask[i] < 0.1f) ? 1.0f : 0.0f;
}

__global__ __launch_bounds__(TPB) void k_downmask(const float* __restrict__ mi,
                                                  float* __restrict__ mo, int Dout) {
  int n = Dout * Dout * Dout;
  int idx = blockIdx.x * TPB + threadIdx.x;
  if (idx >= n) return;
  int Din = Dout * 2;
  int ox = idx % Dout, oy = (idx / Dout) % Dout, oz = idx / (Dout * Dout);
  float v = 0.f;
  for (int kz = 0; kz < 3; kz++) {
    int iz = 2 * oz + kz - 1; if ((unsigned)iz >= (unsigned)Din) continue;
    for (int ky = 0; ky < 3; ky++) {
      int iy = 2 * oy + ky - 1; if ((unsigned)iy >= (unsigned)Din) continue;
      for (int kx = 0; kx < 3; kx++) {
        int ix = 2 * ox + kx - 1; if ((unsigned)ix >= (unsigned)Din) continue;
        v = fmaxf(v, mi[(iz * Din + iy) * Din + ix]);
      }
    }
  }
  mo[idx] = v;
}

__global__ __launch_bounds__(TPB) void k_maskx(const float* __restrict__ x,
                                               const float* __restrict__ m,
                                               float* __restrict__ o,
                                               long total, int vox) {
  long i = blockIdx.x * (long)TPB + threadIdx.x;
  if (i < total) o[i] = x[i] * m[i % vox];
}

__global__ __launch_bounds__(TPB) void k_sumparts(const float* __restrict__ parts,
                                                  float* __restrict__ out,
                                                  long n, int s) {
  long i = blockIdx.x * (long)TPB + threadIdx.x;
  if (i >= n) return;
  float a = 0.f;
  for (int j = 0; j < s; j++) a += parts[(long)j * n + i];
  out[i] = a;
}

// all-classes sum+scatter for the merged convT kernel
__global__ __launch_bounds__(TPB) void k_sumscatA(const float* __restrict__ parts,
                                                  float* __restrict__ out,
                                                  int lgNp, int lgMN, int Dh,
                                                  int lgDh, ParCfg pc) {
  long idx = blockIdx.x * (long)TPB + threadIdx.x;
  if (idx >= (8L << lgMN)) return;
  int cls = (int)(idx >> lgMN);
  int r = (int)(idx & ((1L << lgMN) - 1));
  int co = r >> lgNp;
  int pp = r & ((1 << lgNp) - 1);
  float s = 0.f;
  for (int z = pc.zoff[cls]; z < pc.zoff[cls + 1]; z++)
    s += parts[((long)z << lgMN) + r];
  int px = cls & 1, py = (cls >> 1) & 1, pz = (cls >> 2) & 1;
  int ox = pp & (Dh - 1), oy = (pp >> lgDh) & (Dh - 1), oz = pp >> (2 * lgDh);
  int DF = Dh * 2;
  long fc = ((long)(2 * oz + pz) * DF + (2 * oy + py)) * DF + (2 * ox + px);
  out[(long)co * ((long)DF * DF * DF) + fc] = s;
}

// ================= N=8 weight-streaming path (btd, btc) =================
__global__ __launch_bounds__(TPB) void k_bcol8(const float* __restrict__ in,
                                               float* __restrict__ Bcol,
                                               int K, int Din, int mode) {
  long idx = blockIdx.x * (long)TPB + threadIdx.x;
  if (idx >= (long)K * 8) return;
  int kg = (int)(idx >> 3), pp = (int)(idx & 7);
  int ci = kg / 27, tap = kg - ci * 27;
  int kz = tap / 9, r9 = tap - kz * 9;
  int ky = r9 / 3, kx = r9 - ky * 3;
  int oz = pp >> 2, oy = (pp >> 1) & 1, ox = pp & 1;
  int iz, iy, ix;
  if (mode == 0) { iz = 2 * oz + kz - 1; iy = 2 * oy + ky - 1; ix = 2 * ox + kx - 1; }
  else           { iz = oz + kz - 1;     iy = oy + ky - 1;     ix = ox + kx - 1; }
  float v = 0.f;
  if ((unsigned)iz < (unsigned)Din && (unsigned)iy < (unsigned)Din &&
      (unsigned)ix < (unsigned)Din)
    v = in[(long)ci * Din * Din * Din + ((long)iz * Din + iy) * Din + ix];
  Bcol[idx] = v;
}

// 4 rows per block; register double-buffer prefetch (hides HBM latency).
__global__ __launch_bounds__(TPB) void k_gemv8d(const float* __restrict__ W,
                                                const float* __restrict__ Bcol,
                                                float* __restrict__ part,
                                                int M, int K, int kqPer) {
  const int t = threadIdx.x;
  const int co0 = blockIdx.x * 4;
  const int kq = K >> 2;
  int q0 = blockIdx.y * kqPer;
  int q1 = q0 + kqPer; if (q1 > kq) q1 = kq;
  float acc[4][8];
#pragma unroll
  for (int r = 0; r < 4; r++)
#pragma unroll
    for (int p = 0; p < 8; p++) acc[r][p] = 0.f;
  const float4* W4 = (const float4*)W;

  float4 wc[4], wn[4], bcv[8], bnv[8];
  auto loadW = [&](int i, float4 (&w)[4]) {
#pragma unroll
    for (int r = 0; r < 4; r++) w[r] = W4[(long)(co0 + r) * kq + i];
  };
  auto loadBv = [&](int i, float4 (&b)[8]) {
    const float4* bp = (const float4*)&Bcol[(long)i * 32];
#pragma unroll
    for (int j = 0; j < 8; j++) b[j] = bp[j];
  };

  int i = q0 + t;
  if (i < q1) { loadW(i, wc); loadBv(i, bcv); }
  while (i < q1) {
    const int inx = i + TPB;
    if (inx < q1) { loadW(inx, wn); loadBv(inx, bnv); }   // prefetch
#pragma unroll
    for (int j = 0; j < 4; j++) {
      const float4 b0 = bcv[j * 2];
      const float4 b1 = bcv[j * 2 + 1];
#pragma unroll
      for (int r = 0; r < 4; r++) {
        const float w = (j == 0) ? wc[r].x : (j == 1) ? wc[r].y
                        : (j == 2) ? wc[r].z : wc[r].w;
        acc[r][0] += w * b0.x; acc[r][1] += w * b0.y;
        acc[r][2] += w * b0.z; acc[r][3] += w * b0.w;
        acc[r][4] += w * b1.x; acc[r][5] += w * b1.y;
        acc[r][6] += w * b1.z; acc[r][7] += w * b1.w;
      }
    }
    i = inx;
    if (i < q1) {
#pragma unroll
      for (int r = 0; r < 4; r++) wc[r] = wn[r];
#pragma unroll
      for (int j = 0; j < 8; j++) bcv[j] = bnv[j];
    }
  }
#pragma unroll
  for (int off = 32; off > 0; off >>= 1)
#pragma unroll
    for (int r = 0; r < 4; r++)
#pragma unroll
      for (int p = 0; p < 8; p++) acc[r][p] += __shfl_down(acc[r][p], off);
  __shared__ float Rs[4][4][8];
  if ((t & 63) == 0) {
#pragma unroll
    for (int r = 0; r < 4; r++)
#pragma unroll
      for (int p = 0; p < 8; p++) Rs[t >> 6][r][p] = acc[r][p];
  }
  __syncthreads();
  if (t < 32) {
    int r = t >> 3, p = t & 7;
    part[((long)blockIdx.y * M + co0 + r) * 8 + p] =
        Rs[0][r][p] + Rs[1][r][p] + Rs[2][r][p] + Rs[3][r][p];
  }
}

// ============ up0: dense parity im2colT, Bcol64[K][64] ============
__global__ __launch_bounds__(TPB) void k_bcolT64(const float* __restrict__ in,
                                                 float* __restrict__ B, int K) {
  long idx = blockIdx.x * (long)TPB + threadIdx.x;
  if (idx >= (long)K * 64) return;
  int kg = (int)(idx >> 6), q = (int)(idx & 63);
  int ci = kg / 27, tap = kg - ci * 27;
  int kz = tap / 9, r9 = tap - kz * 9;
  int ky = r9 / 3, kx = r9 - ky * 3;
  int clsT = ((kz & 1) << 2) | ((ky & 1) << 1) | (kx & 1);
  int cls = q >> 3, p = q & 7;
  float v = 0.f;
  if (cls == clsT) {
    int oxh = p & 1, oyh = (p >> 1) & 1, ozh = p >> 2;
    int cx = (kx + (kx & 1)) >> 1;
    int cy = (ky + (ky & 1)) >> 1;
    int cz = (kz + (kz & 1)) >> 1;
    int ix = oxh + cx - 1, iy = oyh + cy - 1, iz = ozh + cz - 1;
    if ((unsigned)ix < 2u && (unsigned)iy < 2u && (unsigned)iz < 2u)
      v = in[(long)ci * 8 + (iz * 2 + iy) * 2 + ix];
  }
  B[idx] = v;
}

// sum split-K partials and scatter [cls][p] -> strided 4^3 grid
__global__ __launch_bounds__(TPB) void k_sumscatT(const float* __restrict__ parts,
                                                  float* __restrict__ out,
                                                  int M, int Z) {
  long idx = blockIdx.x * (long)TPB + threadIdx.x;
  if (idx >= (long)M * 64) return;
  int row = (int)(idx >> 6), q = (int)(idx & 63);
  float s = 0.f;
  for (int z = 0; z < Z; z++) s += parts[((long)z * M + row) * 64 + q];
  int cls = q >> 3, p = q & 7;
  int px = cls & 1, py = (cls >> 1) & 1, pz = (cls >> 2) & 1;
  int oxh = p & 1, oyh = (p >> 1) & 1, ozh = p >> 2;
  int fc = (2 * ozh + pz) * 16 + (2 * oyh + py) * 4 + (2 * oxh + px);
  out[(long)row * 64 + fc] = s;
}

// ================= tiled implicit-GEMM, split-K, reg-prefetch =================
// MODE 0: conv k3 s2 p1   MODE 2: 1x1 concat-fuse / dense B   MODE 3: conv k3 s1 p1
template<int MT, int MODE>
__global__ __launch_bounds__(TPB) void k_gemm(const float* __restrict__ A,
                                              const float* __restrict__ B1,
                                              const float* __restrict__ B2,
                                              float* __restrict__ C,
                                              int M, int N, int K,
                                              int Din, int Dout, int C1,
                                              int kcPer) {
  constexpr int MR = MT / 16;
  constexpr int AEL = (MT == 64) ? 8 : 2;
  __shared__ __align__(16) float At[32][MT];
  __shared__ __align__(16) float Bt[32][64];

  const int t = threadIdx.x;
  const int n0 = blockIdx.x * 64;
  const int m0 = blockIdx.y * MT;

  const int p0 = (t & 15) * 4;
  const int co0 = (t >> 4) * MR;

  const int pb = t & 63;
  const int kb0 = (t >> 6) * 8;
  const int pp = n0 + pb;
  const int oxb = pp & (Dout - 1);
  const int oyb = (pp / Dout) & (Dout - 1);
  const int ozb = pp / (Dout * Dout);

  const int nch = (K + 31) >> 5;
  const int c0 = blockIdx.z * kcPer;
  int c1 = c0 + kcPer; if (c1 > nch) c1 = nch;

  float acc[MR][4];
#pragma unroll
  for (int a = 0; a < MR; a++)
#pragma unroll
    for (int b = 0; b < 4; b++) acc[a][b] = 0.f;

  float raf[AEL];
  float rb[8];
  const int co_a = (MT == 64) ? (t >> 2) : (t & 15);
  const int ka   = (MT == 64) ? ((t & 3) * 8) : ((t >> 4) * 2);
  const long arow = (long)(m0 + co_a) * K;

  auto loadA = [&](int c) {
    const int k0 = c << 5;
    if (MT == 64) {
#pragma unroll
      for (int j = 0; j < 2; j++) {
        const int kg = k0 + ka + j * 4;
        float4 v = (kg < K) ? *(const float4*)&A[arow + kg]
                            : make_float4(0.f, 0.f, 0.f, 0.f);
        raf[j * 4 + 0] = v.x; raf[j * 4 + 1] = v.y;
        raf[j * 4 + 2] = v.z; raf[j * 4 + 3] = v.w;
      }
    } else {
      const int kg = k0 + ka;
      raf[0] = (kg < K) ? A[arow + kg] : 0.f;
      raf[1] = (kg + 1 < K) ? A[arow + kg + 1] : 0.f;
    }
  };

  auto loadB = [&](int c) {
    const int k0 = c << 5;
#pragma unroll
    for (int j = 0; j < 8; j++) {
      const int kg = k0 + kb0 + j;
      float v = 0.f;
      if (kg < K && pp < N) {
        if (MODE == 2) {
          v = (kg < C1) ? B1[(long)kg * N + pp] : B2[(long)(kg - C1) * N + pp];
        } else {
          const int ci = kg / 27;
          const int tap = kg - ci * 27;
          const int kz = tap / 9;
          const int r9 = tap - kz * 9;
          const int ky = r9 / 3;
          const int kx = r9 - ky * 3;
          int iz, iy, ix;
          bool ok;
          if (MODE == 0) {
            iz = 2 * ozb + kz - 1; iy = 2 * oyb + ky - 1; ix = 2 * oxb + kx - 1;
            ok = (unsigned)iz < (unsigned)Din && (unsigned)iy < (unsigned)Din &&
                 (unsigned)ix < (unsigned)Din;
          } else { // MODE 3
            iz = ozb + kz - 1; iy = oyb + ky - 1; ix = oxb + kx - 1;
            ok = (unsigned)iz < (unsigned)Din && (unsigned)iy < (unsigned)Din &&
                 (unsigned)ix < (unsigned)Din;
          }
          if (ok)
            v = B1[(long)ci * Din * Din * Din + ((long)iz * Din + iy) * Din + ix];
        }
      }
      rb[j] = v;
    }
  };

  if (c0 < c1) { loadA(c0); loadB(c0); }

  for (int c = c0; c < c1; ++c) {
    __syncthreads();
#pragma unroll
    for (int j = 0; j < AEL; j++) At[ka + j][co_a] = raf[j];
#pragma unroll
    for (int j = 0; j < 8; j++) Bt[kb0 + j][pb] = rb[j];
    if (c + 1 < c1) { loadA(c + 1); loadB(c + 1); }
    __syncthreads();
#pragma unroll
    for (int kk = 0; kk < 32; ++kk) {
      const float4 b4 = *(const float4*)&Bt[kk][p0];
      if (MR == 4) {
        const float4 a4 = *(const float4*)&At[kk][co0];
        acc[0][0] += a4.x * b4.x; acc[0][1] += a4.x * b4.y;
        acc[0][2] += a4.x * b4.z; acc[0][3] += a4.x * b4.w;
        acc[1][0] += a4.y * b4.x; acc[1][1] += a4.y * b4.y;
        acc[1][2] += a4.y * b4.z; acc[1][3] += a4.y * b4.w;
        acc[2][0] += a4.z * b4.x; acc[2][1] += a4.z * b4.y;
        acc[2][2] += a4.z * b4.z; acc[2][3] += a4.z * b4.w;
        acc[3][0] += a4.w * b4.x; acc[3][1] += a4.w * b4.y;
        acc[3][2] += a4.w * b4.z; acc[3][3] += a4.w * b4.w;
      } else {
        const float a = At[kk][co0];
        acc[0][0] += a * b4.x; acc[0][1] += a * b4.y;
        acc[0][2] += a * b4.z; acc[0][3] += a * b4.w;
      }
    }
  }

  float* Cz = C + (long)blockIdx.z * ((long)M * N);
#pragma unroll
  for (int mr = 0; mr < MR; mr++) {
    if (n0 + p0 < N) {
      float4 v = make_float4(acc[mr][0], acc[mr][1], acc[mr][2], acc[mr][3]);
      *(float4*)&Cz[(long)(m0 + co0 + mr) * N + n0 + p0] = v;
    }
  }
}

// ================= merged convT-parity GEMM (up1..up3), 3D grid ============
__global__ __launch_bounds__(TPB) void k_gemmTm(const float* __restrict__ A,
                                                const float* __restrict__ B1,
                                                float* __restrict__ C,
                                                int M, int N, int Cin, int Din,
                                                ParCfg pc) {
  __shared__ __align__(16) float At[32][64];
  __shared__ __align__(16) float Bt[32][64];

  const int t = threadIdx.x;
  const int n0 = blockIdx.x * 64;
  const int m0 = blockIdx.y * 64;
  const int z = blockIdx.z;

  int cls = 0;
#pragma unroll
  for (int c = 1; c < 8; c++) if (z >= pc.zoff[c]) cls = c;
  const int zi = z - pc.zoff[cls];
  const int kperc = pc.kper[cls];

  const int px = cls & 1, py = (cls >> 1) & 1, pz = (cls >> 2) & 1;
  const int lgnx = 1 - px, lgny = 1 - py;
  const int lgT = lgnx + lgny + (1 - pz);
  const int T = 1 << lgT;
  const int K = Cin << lgT;
  const int nch = K >> 5;

  const int p0 = (t & 15) * 4;
  const int co0 = (t >> 4) * 4;
  const int pb = t & 63;
  const int kb0 = (t >> 6) * 8;      // wave-uniform
  const int pp = n0 + pb;
  const int oxb = pp & (Din - 1);
  const int oyb = (pp / Din) & (Din - 1);
  const int ozb = pp / (Din * Din);
  const long vin = (long)Din * Din * Din;

  const int bz = ozb - 1 + pz, by = oyb - 1 + py, bx = oxb - 1 + px;
  const long laneOff = (long)bz * Din * Din + (long)by * Din + bx;
  unsigned vmask = 0;
  if (pp < N) {
    int nz_ = pz ? 1 : 2, ny_ = py ? 1 : 2, nx_ = px ? 1 : 2;
    for (int tz = 0; tz < nz_; tz++)
      for (int ty = 0; ty < ny_; ty++)
        for (int tx = 0; tx < nx_; tx++) {
          bool ok = (unsigned)(bz + tz) < (unsigned)Din &&
                    (unsigned)(by + ty) < (unsigned)Din &&
                    (unsigned)(bx + tx) < (unsigned)Din;
          if (ok) vmask |= 1u << ((tz << (lgny + lgnx)) | (ty << lgnx) | tx);
        }
  }

  const int c0 = zi * kperc;
  int c1 = c0 + kperc; if (c1 > nch) c1 = nch;

  float acc[4][4];
#pragma unroll
  for (int a = 0; a < 4; a++)
#pragma unroll
    for (int b = 0; b < 4; b++) acc[a][b] = 0.f;

  float raf[8];
  float rb[8];
  const int co_a = t & 63;
  const int ka   = (t >> 6) * 8;
  const long abase = (long)(m0 + co_a) * Cin * 27;

  auto loadA = [&](int c) {
    const int k0 = c << 5;
#pragma unroll
    for (int j = 0; j < 8; j++) {
      const int kg = k0 + ka + j;
      float v = 0.f;
      if (kg < K) {
        int ci = kg >> lgT;
        int tt = kg & (T - 1);
        int tx = tt & ((1 << lgnx) - 1);
        int r = tt >> lgnx;
        int ty = r & ((1 << lgny) - 1);
        int tz = r >> lgny;
        int kx = px ? 1 : (tx << 1);
        int ky = py ? 1 : (ty << 1);
        int kz = pz ? 1 : (tz << 1);
        v = A[abase + ci * 27 + (kz * 3 + ky) * 3 + kx];
      }
      raf[j] = v;
    }
  };

  auto loadB = [&](int c) {
    const int k0 = c << 5;
#pragma unroll
    for (int j = 0; j < 8; j++) {
      const int kg = k0 + kb0 + j;
      float v = 0.f;
      if (kg < K) {
        int ci = kg >> lgT;
        int tt = kg & (T - 1);
        int tx = tt & ((1 << lgnx) - 1);
        int r = tt >> lgnx;
        int ty = r & ((1 << lgny) - 1);
        int tz = r >> lgny;
        long base = (long)ci * vin + (long)tz * Din * Din + ty * Din + tx;
        if ((vmask >> tt) & 1) v = B1[base + laneOff];
      }
      rb[j] = v;
    }
  };

  if (c0 < c1) { loadA(c0); loadB(c0); }

  for (int c = c0; c < c1; ++c) {
    __syncthreads();
#pragma unroll
    for (int j = 0; j < 8; j++) At[ka + j][co_a] = raf[j];
#pragma unroll
    for (int j = 0; j < 8; j++) Bt[kb0 + j][pb] = rb[j];
    if (c + 1 < c1) { loadA(c + 1); loadB(c + 1); }
    __syncthreads();
#pragma unroll
    for (int kk = 0; kk < 32; ++kk) {
      const float4 b4 = *(const float4*)&Bt[kk][p0];
      const float4 a4 = *(const float4*)&At[kk][co0];
      acc[0][0] += a4.x * b4.x; acc[0][1] += a4.x * b4.y;
      acc[0][2] += a4.x * b4.z; acc[0][3] += a4.x * b4.w;
      acc[1][0] += a4.y * b4.x; acc[1][1] += a4.y * b4.y;
      acc[1][2] += a4.y * b4.z; acc[1][3] += a4.y * b4.w;
      acc[2][0] += a4.z * b4.x; acc[2][1] += a4.z * b4.y;
      acc[2][2] += a4.z * b4.z; acc[2][3] += a4.z * b4.w;
      acc[3][0] += a4.w * b4.x; acc[3][1] += a4.w * b4.y;
      acc[3][2] += a4.w * b4.z; acc[3][3] += a4.w * b4.w;
    }
  }

  float* Cz = C + (long)z * ((long)M * N);
#pragma unroll
  for (int mr = 0; mr < 4; mr++) {
    if (n0 + p0 < N) {
      float4 v = make_float4(acc[mr][0], acc[mr][1], acc[mr][2], acc[mr][3]);
      *(float4*)&Cz[(long)(m0 + co0 + mr) * N + n0 + p0] = v;
    }
  }
}

// ================= final-up: M=16, per-column, class-balanced =================
// grid.z = 9: z 0..1 -> class 0 split into two ci-halves, coalesced partials;
// z 2..8 -> classes 1..7 direct strided write.  FMA order per ci unchanged.
__global__ __launch_bounds__(TPB) void k_finup(const float* __restrict__ A,
                                               const float* __restrict__ B1,
                                               float* __restrict__ C,
                                               float* __restrict__ Cpart) {
  __shared__ __align__(16) float Ws[8192];
  const int zb = blockIdx.z;
  const bool isPart = (zb < 2);
  const int cls = isPart ? 0 : (zb - 1);
  const int ci0 = isPart ? zb * 32 : 0;
  const int ci1 = isPart ? ci0 + 32 : 64;
  const int px = cls & 1, py = (cls >> 1) & 1, pz = (cls >> 2) & 1;
  const int lgnx = 1 - px, lgny = 1 - py;
  const int lgT = lgnx + lgny + (1 - pz);
  const int T = 1 << lgT;
  const int K = 64 << lgT;

  for (int idx = threadIdx.x; idx < K * 16; idx += TPB) {
    int k = idx >> 4, co = idx & 15;
    int ci = k >> lgT;
    int tt = k & (T - 1);
    int tx = tt & ((1 << lgnx) - 1);
    int r = tt >> lgnx;
    int ty = r & ((1 << lgny) - 1);
    int tz = r >> lgny;
    int kx = px ? 1 : (tx << 1);
    int ky = py ? 1 : (ty << 1);
    int kz = pz ? 1 : (tz << 1);
    Ws[idx] = A[((long)co * 64 + ci) * 27 + (kz * 3 + ky) * 3 + kx];
  }

  const int pp = blockIdx.x * TPB + threadIdx.x;
  const int oxb = pp & 31, oyb = (pp >> 5) & 31, ozb = pp >> 10;
  const int bz = ozb - 1 + pz, by = oyb - 1 + py, bx = oxb - 1 + px;
  const long laneOff = (long)bz * 1024 + by * 32 + bx;
  unsigned vmask = 0;
  {
    int nz_ = pz ? 1 : 2, ny_ = py ? 1 : 2, nx_ = px ? 1 : 2;
    for (int tz = 0; tz < nz_; tz++)
      for (int ty = 0; ty < ny_; ty++)
        for (int tx = 0; tx < nx_; tx++) {
          bool ok = (unsigned)(bz + tz) < 32u && (unsigned)(by + ty) < 32u &&
                    (unsigned)(bx + tx) < 32u;
          if (ok) vmask |= 1u << ((tz << (lgny + lgnx)) | (ty << lgnx) | tx);
        }
  }

  int toff[8];
#pragma unroll
  for (int tt = 0; tt < 8; tt++) {
    int tx = tt & ((1 << lgnx) - 1);
    int r = tt >> lgnx;
    int ty = r & ((1 << lgny) - 1);
    int tz = r >> lgny;
    toff[tt] = tz * 1024 + ty * 32 + tx;
  }
  __syncthreads();

  float acc[16];
#pragma unroll
  for (int co = 0; co < 16; co++) acc[co] = 0.f;

  float bcur[8], bnxt[8];
  auto loadG = [&](int ci, float (&bv)[8]) {
#pragma unroll
    for (int tt = 0; tt < 8; tt++) {
      if (tt < T)
        bv[tt] = ((vmask >> tt) & 1)
                     ? B1[(long)ci * 32768 + toff[tt] + laneOff] : 0.f;
      else
        bv[tt] = 0.f;
    }
  };

  loadG(ci0, bcur);
  for (int ci = ci0; ci < ci1; ci++) {
    if (ci + 1 < ci1) loadG(ci + 1, bnxt);   // prefetch: hides L2 latency
#pragma unroll
    for (int tt = 0; tt < 8; tt++) {
      if (tt < T) {
        const float b = bcur[tt];
        const float4* wp = (const float4*)&Ws[((ci << lgT) + tt) * 16];
#pragma unroll
        for (int q = 0; q < 4; q++) {
          float4 w = wp[q];
          acc[q * 4 + 0] += w.x * b;
          acc[q * 4 + 1] += w.y * b;
          acc[q * 4 + 2] += w.z * b;
          acc[q * 4 + 3] += w.w * b;
        }
      }
    }
#pragma unroll
    for (int tt = 0; tt < 8; tt++) bcur[tt] = bnxt[tt];
  }

  if (isPart) {
    float* cp = Cpart + (long)zb * 524288;   // [z][16][32768], coalesced
#pragma unroll
    for (int co = 0; co < 16; co++) cp[(long)co * 32768 + pp] = acc[co];
  } else {
    const long fc = ((long)(2 * ozb + pz) * 64 + (2 * oyb + py)) * 64 +
                    (2 * oxb + px);
#pragma unroll
    for (int co = 0; co < 16; co++) C[(long)co * 262144 + fc] = acc[co];
  }
}

// sum the two class-0 ci-half partials and scatter (px=py=pz=0)
__global__ __launch_bounds__(TPB) void k_finsum0(const float* __restrict__ parts,
                                                 float* __restrict__ C) {
  long idx = blockIdx.x * (long)TPB + threadIdx.x;
  if (idx >= 524288) return;                 // 16 * 32768
  int co = (int)(idx >> 15), pp = (int)(idx & 32767);
  float s = parts[idx] + parts[524288 + idx];
  int oxb = pp & 31, oyb = (pp >> 5) & 31, ozb = pp >> 10;
  long fc = (long)(2 * ozb) * 4096 + (2 * oyb) * 64 + (2 * oxb);
  C[(long)co * 262144 + fc] = s;
}

// ================= hierarchical masked BN stats =================
__global__ __launch_bounds__(TPB) void k_stats1(const float* __restrict__ a,
                                                const float* __restrict__ m,
                                                float* __restrict__ part,
                                                float* __restrict__ partM,
                                                int vox, int chunk) {
  const int s = blockIdx.x, c = blockIdx.y;
  const float* ap = a + (long)c * vox + (long)s * chunk;
  const float* mp = m + (long)s * chunk;
  float s0 = 0.f, s1 = 0.f, sm = 0.f;
  for (int i = threadIdx.x; i < chunk; i += TPB) {
    float mv = mp[i];
    float v = ap[i] * mv;
    s0 += v; s1 += v * v; sm += mv;
  }
  __shared__ float sh0[TPB], sh1[TPB], sh2[TPB];
  sh0[threadIdx.x] = s0; sh1[threadIdx.x] = s1; sh2[threadIdx.x] = sm;
  __syncthreads();
  for (int off = TPB / 2; off > 0; off >>= 1) {
    if (threadIdx.x < off) {
      sh0[threadIdx.x] += sh0[threadIdx.x + off];
      sh1[threadIdx.x] += sh1[threadIdx.x + off];
      sh2[threadIdx.x] += sh2[threadIdx.x + off];
    }
    __syncthreads();
  }
  if (threadIdx.x == 0) {
    const int S = gridDim.x;
    part[(c * S + s) * 2] = sh0[0];
    part[(c * S + s) * 2 + 1] = sh1[0];
    if (c == 0) partM[s] = sh2[0];
  }
}

__global__ __launch_bounds__(64) void k_stats2(const float* __restrict__ part,
                                               const float* __restrict__ partM,
                                               float* __restrict__ stats, int S) {
  const int c = blockIdx.x, t = threadIdx.x;
  float s0 = 0.f, s1 = 0.f, sm = 0.f;
  for (int s = t; s < S; s += 64) {
    s0 += part[(c * S + s) * 2];
    s1 += part[(c * S + s) * 2 + 1];
    sm += partM[s];
  }
  for (int off = 32; off > 0; off >>= 1) {
    s0 += __shfl_down(s0, off);
    s1 += __shfl_down(s1, off);
    sm += __shfl_down(sm, off);
  }
  if (t == 0) {
    float n = fmaxf(sm, 1.f);
    float mu = s0 / n;
    float var = fmaxf(s1 / n - mu * mu, 0.f);
    stats[2 * c] = mu;
    stats[2 * c + 1] = rsqrtf(var + 1e-5f);
  }
}

__global__ __launch_bounds__(TPB) void k_apply(float* __restrict__ a,
                                               const float* __restrict__ m,
                                               const float* __restrict__ stats,
                                               int vox, long total) {
  long idx = blockIdx.x * (long)TPB + threadIdx.x;
  if (idx >= total) return;
  int c = (int)(idx / vox);
  int p = (int)(idx % vox);
  float v = (a[idx] - stats[2 * c]) * stats[2 * c + 1];
  a[idx] = fmaxf(v, 0.f) * m[p];
}

__global__ __launch_bounds__(TPB) void k_apply_out(const float* __restrict__ a,
                                                   const float* __restrict__ m,
                                                   const float* __restrict__ stats,
                                                   float* __restrict__ out,
                                                   int vox, long total) {
  long idx = blockIdx.x * (long)TPB + threadIdx.x;
  if (idx >= total) return;
  int c = (int)(idx / vox);
  int p = (int)(idx % vox);
  float v = (a[idx] - stats[2 * c]) * stats[2 * c + 1];
  out[idx] = fmaxf(v, 0.f) * m[p];
}

// ================= workspace layout (floats) =================
constexpr long o_m0 = 0;
constexpr long o_m1 = 262144;
constexpr long o_m2 = 294912;
constexpr long o_m3 = 299008;
constexpr long o_m4 = 299520;
constexpr long o_m5 = 299584;
constexpr long o_st = 299592;
constexpr long o_A  = 301696;     // 2M: xm -> scratch -> u3 -> fin
constexpr long o_B  = 2398848;    // 2M: a0
constexpr long o_C  = 4496000;    // 512K: a1; +dead span = finup cls0 partials
constexpr long o_D  = 5020288;    // 128K: a2
constexpr long o_E  = 5151360;    // 32K: a3
constexpr long o_F  = 5184128;    // 8K: a4
constexpr long o_G  = 5192320;    // 8K: a5
constexpr long o_H  = 5200512;    // 32K: u0
constexpr long o_I  = 5233280;    // 32K: f0
constexpr long o_J  = 5266048;    // 128K: u1
constexpr long o_K  = 5397120;    // 128K: f1
constexpr long o_L  = 5528192;    // 512K: u2
constexpr long o_M  = 6052480;    // 512K: f2
constexpr long o_N  = 6576768;    // 2M: f3 (up0/up3 scratch before fu3)
constexpr long o_P  = 8673920;    // BN partials
constexpr long o_PM = 8690304;
constexpr long o_S  = 8690368;    // tail scratch (size = ws_size/4 - o_S)
constexpr long o_fin = o_A;

extern "C" void kernel_launch(void* const* d_in, const int* in_sizes, int n_in,
                              void* d_out, int out_size, void* d_ws, size_t ws_size,
                              hipStream_t stream) {
  const float* x      = (const float*)d_in[0];
  const float* mask   = (const float*)d_in[1];
  const float* w_enc0 = (const float*)d_in[2];
  const float* w_enc1 = (const float*)d_in[3];
  const float* w_enc2 = (const float*)d_in[4];
  const float* w_enc3 = (const float*)d_in[5];
  const float* w_btd  = (const float*)d_in[6];
  const float* w_btc  = (const float*)d_in[7];
  const float* w_up0  = (const float*)d_in[8];
  const float* w_fu0  = (const float*)d_in[9];
  const float* w_up1  = (const float*)d_in[10];
  const float* w_fu1  = (const float*)d_in[11];
  const float* w_up2  = (const float*)d_in[12];
  const float* w_fu2  = (const float*)d_in[13];
  const float* w_up3  = (const float*)d_in[14];
  const float* w_fu3  = (const float*)d_in[15];
  const float* w_fin  = (const float*)d_in[16];

  float* ws = (float*)d_ws;
  float* st = ws + o_st;
  float* out = (float*)d_out;

  long tailCap = (long)(ws_size / 4) - o_S;
  if (tailCap < 0) tailCap = 0;

  auto blocks = [](long n) { return (unsigned)((n + TPB - 1) / TPB); };

  // masks
  k_mask0<<<blocks(262144), TPB, 0, stream>>>(mask, ws + o_m0, 262144);
  k_downmask<<<blocks(32768), TPB, 0, stream>>>(ws + o_m0, ws + o_m1, 32);
  k_downmask<<<blocks(4096), TPB, 0, stream>>>(ws + o_m1, ws + o_m2, 16);
  k_downmask<<<blocks(512), TPB, 0, stream>>>(ws + o_m2, ws + o_m3, 8);
  k_downmask<<<blocks(64), TPB, 0, stream>>>(ws + o_m3, ws + o_m4, 4);
  k_downmask<<<blocks(8), TPB, 0, stream>>>(ws + o_m4, ws + o_m5, 2);

  // masked input -> A
  k_maskx<<<blocks(8L * 262144), TPB, 0, stream>>>(x, ws + o_m0, ws + o_A,
                                                   8L * 262144, 262144);

  auto stats = [&](const float* a, const float* m, int C, int vox) {
    int S = vox / TPB; if (S < 1) S = 1; if (S > 64) S = 64;
    int chunk = vox / S;
    dim3 g(S, C);
    k_stats1<<<g, TPB, 0, stream>>>(a, m, ws + o_P, ws + o_PM, vox, chunk);
    k_stats2<<<C, 64, 0, stream>>>(ws + o_P, ws + o_PM, st, S);
  };
  auto bnrelu = [&](float* a, const float* m, int C, int vox) {
    stats(a, m, C, vox);
    long total = (long)C * vox;
    k_apply<<<blocks(total), TPB, 0, stream>>>(a, m, st, vox, total);
  };

#define GEMM(MT, MODE, A_, B1_, B2_, O_, M_, N_, K_, DIN_, DOUT_, C1_, Z_)   \
  do {                                                                        \
    int nch_ = ((K_) + 31) >> 5;                                              \
    int kper_ = (nch_ + (Z_) - 1) / (Z_);                                     \
    dim3 g_(((N_) + 63) / 64, (M_) / (MT), (Z_));                             \
    float* dst_ = ((Z_) > 1) ? (ws + o_A) : (O_);                             \
    k_gemm<MT, MODE><<<g_, TPB, 0, stream>>>(A_, B1_, B2_, dst_, M_, N_, K_,  \
                                             DIN_, DOUT_, C1_, kper_);        \
    if ((Z_) > 1)                                                             \
      k_sumparts<<<blocks((long)(M_) * (N_)), TPB, 0, stream>>>(              \
          ws + o_A, O_, (long)(M_) * (N_), (Z_));                             \
  } while (0)

  // merged convT: adaptive split-K depth (3D grid)
  auto convTmerged = [&](const float* w, const float* in, float* o, int M,
                         int Cin, int Dh, int dMin, float* scrP, long scrPcap) {
    int lgDh = 31 - __builtin_clz(Dh);
    int Np = Dh * Dh * Dh;
    long unit = (long)M * Np;
    float* scr = scrP;
    long cap = scrPcap;
    if (tailCap > cap) { scr = ws + o_S; cap = tailCap; }
    int d = dMin, slices = 0;
    for (;;) {
      slices = 0;
      for (int c = 0; c < 8; c++) {
        int px = c & 1, py = (c >> 1) & 1, pz = (c >> 2) & 1;
        int T = 1 << ((1 - px) + (1 - py) + (1 - pz));
        int nch = (Cin * T) >> 5;
        slices += (nch + d - 1) / d;
      }
      if ((long)slices * unit <= cap || d >= 256) break;
      d <<= 1;
    }
    ParCfg pc;
    int acc = 0;
    for (int c = 0; c < 8; c++) {
      pc.zoff[c] = acc;
      int px = c & 1, py = (c >> 1) & 1, pz = (c >> 2) & 1;
      int T = 1 << ((1 - px) + (1 - py) + (1 - pz));
      int nch = (Cin * T) >> 5;
      pc.kper[c] = d;
      acc += (nch + d - 1) / d;
    }
    pc.zoff[8] = acc;
    dim3 g((Np + 63) / 64, M / 64, acc);
    k_gemmTm<<<g, TPB, 0, stream>>>(w, in, scr, M, Np, Cin, Dh, pc);
    int lgNp = 3 * lgDh;
    int lgMN = lgNp + (31 - __builtin_clz(M));
    k_sumscatA<<<blocks(8L << lgMN), TPB, 0, stream>>>(scr, o, lgNp, lgMN,
                                                       Dh, lgDh, pc);
  };

  // N=8 weight-streaming GEMV, 4 rows/block (btd, btc), Z=4, reg double-buffer
  auto gemv8 = [&](const float* w, const float* in, float* o, int M, int Cin,
                   int Din, int mode, int Z) {
    int K = Cin * 27;
    float* bcol = ws + o_A;
    float* parts = ws + o_A + 262144;
    k_bcol8<<<blocks((long)K * 8), TPB, 0, stream>>>(in, bcol, K, Din, mode);
    int kq = K >> 2;
    int kqPer = (kq + Z - 1) / Z;
    dim3 g(M / 4, Z);
    k_gemv8d<<<g, TPB, 0, stream>>>(w, bcol, parts, M, K, kqPer);
    k_sumparts<<<blocks((long)M * 8), TPB, 0, stream>>>(parts, o, (long)M * 8, Z);
  };

  // ---------------- encoder ----------------
  GEMM(64, 0, w_enc0, ws + o_A, nullptr, ws + o_B, 64, 32768, 8 * 27, 64, 32, 0, 1);
  bnrelu(ws + o_B, ws + o_m1, 64, 32768);
  GEMM(64, 0, w_enc1, ws + o_B, nullptr, ws + o_C, 128, 4096, 64 * 27, 32, 16, 0, 4);
  bnrelu(ws + o_C, ws + o_m2, 128, 4096);
  GEMM(64, 0, w_enc2, ws + o_C, nullptr, ws + o_D, 256, 512, 128 * 27, 16, 8, 0, 16);
  bnrelu(ws + o_D, ws + o_m3, 256, 512);
  GEMM(64, 0, w_enc3, ws + o_D, nullptr, ws + o_E, 512, 64, 256 * 27, 8, 4, 0, 64);
  bnrelu(ws + o_E, ws + o_m4, 512, 64);

  // ---------------- bottleneck (4-row weight streamers, Z=4) ----------------
  gemv8(w_btd, ws + o_E, ws + o_F, 1024, 512, 4, 0, 4);
  bnrelu(ws + o_F, ws + o_m5, 1024, 8);
  gemv8(w_btc, ws + o_F, ws + o_G, 1024, 1024, 2, 3, 4);
  bnrelu(ws + o_G, ws + o_m5, 1024, 8);

  // ---------------- decoder ----------------
  // up0: dense parity GEMM (M=512, N=64, K=27648) through k_gemm MODE 2
  {
    int K = 1024 * 27;
    float* bcol = ws + o_A;                 // 1769472 floats
    float* parts = ws + o_N;                // 64*512*64 = 2097152 floats
    k_bcolT64<<<blocks((long)K * 64), TPB, 0, stream>>>(ws + o_G, bcol, K);
    int nch = (K + 31) >> 5;                // 864
    int Z = 64;
    int kper = (nch + Z - 1) / Z;           // 14
    dim3 g(1, 512 / 64, Z);
    k_gemm<64, 2><<<g, TPB, 0, stream>>>(w_up0, bcol, nullptr, parts,
                                         512, 64, K, 4, 4, K, kper);
    k_sumscatT<<<blocks(512L * 64), TPB, 0, stream>>>(parts, ws + o_H, 512, Z);
  }
  bnrelu(ws + o_H, ws + o_m4, 512, 64);
  GEMM(64, 2, w_fu0, ws + o_H, ws + o_E, ws + o_I, 512, 64, 1024, 4, 4, 512, 32);
  bnrelu(ws + o_I, ws + o_m4, 512, 64);

  convTmerged(w_up1, ws + o_I, ws + o_J, 256, 512, 4, 2, ws + o_A, 2097152);
  bnrelu(ws + o_J, ws + o_m3, 256, 512);
  GEMM(64, 2, w_fu1, ws + o_J, ws + o_D, ws + o_K, 256, 512, 512, 8, 8, 256, 16);
  bnrelu(ws + o_K, ws + o_m3, 256, 512);

  convTmerged(w_up2, ws + o_K, ws + o_L, 128, 256, 8, 2, ws + o_A, 2097152);
  bnrelu(ws + o_L, ws + o_m2, 128, 4096);
  GEMM(64, 2, w_fu2, ws + o_L, ws + o_C, ws + o_M, 128, 4096, 256, 16, 16, 128, 2);
  bnrelu(ws + o_M, ws + o_m2, 128, 4096);

  // up3: o_N scratch (8 slices, d=32) unless tail scratch allows deeper
  convTmerged(w_up3, ws + o_M, ws + o_A, 64, 128, 16, 4, ws + o_N, 2097152);
  bnrelu(ws + o_A, ws + o_m1, 64, 32768);
  GEMM(64, 2, w_fu3, ws + o_A, ws + o_B, ws + o_N, 64, 32768, 128, 32, 32, 64, 1);
  bnrelu(ws + o_N, ws + o_m1, 64, 32768);

  // ---------------- final up: class-balanced (cls0 split, partials @ o_C) ----
  {
    dim3 g(32768 / TPB, 1, 9);
    k_finup<<<g, TPB, 0, stream>>>(w_fin, ws + o_N, ws + o_fin, ws + o_C);
    k_finsum0<<<blocks(524288), TPB, 0, stream>>>(ws + o_C, ws + o_fin);
  }
  {
    int vox = 262144, C = 16;
    int S = 64, chunk = vox / S;
    dim3 g(S, C);
    k_stats1<<<g, TPB, 0, stream>>>(ws + o_fin, ws + o_m0, ws + o_P, ws + o_PM,
                                    vox, chunk);
    k_stats2<<<C, 64, 0, stream>>>(ws + o_P, ws + o_PM, st, S);
    long total = (long)C * vox;
    k_apply_out<<<blocks(total), TPB, 0, stream>>>(ws + o_fin, ws + o_m0, st,
                                                   out, vox, total);
  }
#undef GEMM
}